// Round 4
// baseline (7165.794 us; speedup 1.0000x reference)
//
#include <hip/hip_runtime.h>
#include <hip/hip_bf16.h>
#include <stdint.h>
#include <math.h>

#define NBATCH 512
#define NS 256
#define NE 128
#define NH 128
#define NSTEPS 255
#define NEGINF -1e8f
#define SENT_NEG -1e30f

// ---------------- threefry2x32 (partitionable path, verified r2/r3) ----------------
__device__ __forceinline__ uint32_t rotl32(uint32_t x, uint32_t r) {
  return (x << r) | (x >> (32u - r));
}

__device__ __forceinline__ void tf2x32(uint32_t k0, uint32_t k1,
                                       uint32_t x0, uint32_t x1,
                                       uint32_t& o0, uint32_t& o1) {
  uint32_t ks2 = k0 ^ k1 ^ 0x1BD11BDAu;
  x0 += k0; x1 += k1;
#define TF_R4(a,b,c,d) \
  x0 += x1; x1 = rotl32(x1,a); x1 ^= x0; \
  x0 += x1; x1 = rotl32(x1,b); x1 ^= x0; \
  x0 += x1; x1 = rotl32(x1,c); x1 ^= x0; \
  x0 += x1; x1 = rotl32(x1,d); x1 ^= x0;
  TF_R4(13,15,26,6)   x0 += k1;  x1 += ks2 + 1u;
  TF_R4(17,29,16,24)  x0 += ks2; x1 += k0 + 2u;
  TF_R4(13,15,26,6)   x0 += k0;  x1 += k1 + 3u;
  TF_R4(17,29,16,24)  x0 += k1;  x1 += ks2 + 4u;
  TF_R4(13,15,26,6)   x0 += ks2; x1 += k0 + 5u;
#undef TF_R4
  o0 = x0; o1 = x1;
}

// tanh via hw exp2 + rcp + 1 Newton step: <=1 ulp (verified exact-index r3)
__device__ __forceinline__ float nr_tanh(float x) {
  const float Chi = 2.8853900432586670f;      // float(2*log2(e))
  const float Clo = 3.8519259822379735e-08f;  // residual
  float m = fmaf(x, Chi, x * Clo);
  m = fminf(m, 126.0f);
  float tt = __builtin_amdgcn_exp2f(m);
  float d  = tt + 1.0f;
  float r  = __builtin_amdgcn_rcpf(d);
  r = r * fmaf(-d, r, 2.0f);
  return fmaf(-2.0f, r, 1.0f);
}

// ======================= precompute kernels (unchanged from r3) =======================
__global__ void k1_mats(const float* __restrict__ Wv, const float* __restrict__ Wq,
                        const float* __restrict__ liw, const float* __restrict__ bvv,
                        float* __restrict__ M1T, float* __restrict__ M2T,
                        float* __restrict__ rest0) {
  int e = blockIdx.x, h = threadIdx.x;
  __shared__ float wrow[NE];
  if (e < 256) {
    wrow[h] = Wv[e * NE + h];
    __syncthreads();
    double a = 0.0;
    for (int k = 0; k < NE; ++k) a += (double)wrow[k] * (double)Wq[k * NH + h];
    if (e < 128) M1T[h * NE + e] = (float)a;
    else         M2T[h * NE + (e - 128)] = (float)a;
  } else {
    double a = 0.0;
    for (int k = 0; k < 2 * NE; ++k) a += (double)liw[k] * (double)Wv[k * NE + h];
    rest0[h] = (float)a + bvv[h];
  }
}

__global__ void k2_base(const float* __restrict__ cv, const float* __restrict__ Wc,
                        const float* __restrict__ bc, const float* __restrict__ bvv,
                        const float* __restrict__ Wq, const float* __restrict__ rest0,
                        double* __restrict__ qqbase, float* __restrict__ qq0) {
  int b = blockIdx.x, h = threadIdx.x;
  int b256 = b << 8;
  __shared__ float meanL[NE], hbarL[NE];
  double ms = 0.0;
  for (int s = 0; s < NS; ++s) ms += (double)cv[((size_t)b256 + s) * NE + h];
  meanL[h] = (float)(ms * (1.0 / 256.0));
  __syncthreads();
  double a = 0.0;
  for (int e = 0; e < NE; ++e) a += (double)meanL[e] * (double)Wc[e * NE + h];
  hbarL[h] = (float)a + bc[h];
  __syncthreads();
  double ab = 0.0, a0 = 0.0;
  for (int k = 0; k < NE; ++k) {
    double w = (double)Wq[k * NH + h];
    ab += (double)(hbarL[k] + bvv[k]) * w;
    a0 += (double)(hbarL[k] + rest0[k]) * w;
  }
  qqbase[(size_t)b * NH + h] = ab;
  qq0[(size_t)b * NH + h] = (float)a0;
}

// ======================= main decode kernel =======================
struct MainSh {
  alignas(16) float  qq[NH];
  alignas(16) float  vvf[NH];
  alignas(8)  double partA[NS];     // indexed by list position i
  float  logitArr[NS];              // indexed by ROW id
  alignas(8)  double base128[NH];
  uint2  keyL[NSTEPS];
  float  redV[8];
  float  redS[8];
  int    redI[8];
};

struct PreSh {
  float cvS[NS][33];
  float wS[32][NH];
};

__global__ __launch_bounds__(512, 4)
void decode_main(const float* __restrict__ cv,
                 const float* __restrict__ mask_in,
                 const float* __restrict__ Wref,
                 const float* __restrict__ vvec,
                 const double* __restrict__ qqbase,
                 const float* __restrict__ M1T,
                 const float* __restrict__ M2T,
                 const float* __restrict__ qq0,
                 float* __restrict__ out) {
  const int b = blockIdx.x;
  const int t = threadIdx.x;
  const int b256 = b << 8;
  const int i = t >> 1;          // list position (pair index)
  const int halfo = t & 1;       // which 64-wide h-slice of the pair
  const int hb = halfo << 6;

  __shared__ union { PreSh pre; MainSh m; } sh;
  // persistent (outside union): compaction state, double-buffered by step parity
  __shared__ short rowIdA[NS], rowIdB[NS], posA[NS], posB[NS];
  __shared__ int nActSh[2], jSh[2], tmp8[8];
  __shared__ alignas(16) float refScratch[NE];

  // ---------- build initial active-row list ----------
  bool act0 = false;
  if (t < NS) {
    act0 = !((t == 0) || (mask_in[(size_t)b256 + t] > 0.0f));
    uint64_t mb = __ballot(act0);
    int lane = t & 63, w = t >> 6;
    int pre = __popcll(mb & (((uint64_t)1 << lane) - 1));
    if (lane == 0) tmp8[w] = (int)__popcll(mb);
    posA[t] = (short)pre;  // stash lane-prefix temporarily
  }
  __syncthreads();
  if (t < NS) {
    int base = 0;
    for (int k = 0; k < (t >> 6); ++k) base += tmp8[k];
    int p = base + (int)posA[t];
    if (act0) { rowIdA[p] = (short)t; }
    posA[t] = (short)p;  // valid only for active rows (others never read)
  }
  if (t == 0) {
    nActSh[0] = tmp8[0] + tmp8[1] + tmp8[2] + tmp8[3];
    jSh[0] = -1;
  }
  __syncthreads();
  const int nAct0 = nActSh[0];

  // ---------- Phase 1: refr[j] = ref[myRow0][hb+j] (bit-identical chunking) ----------
  const int myRow0 = (i < nAct0) ? (int)rowIdA[i] : 0;
  float refr[64];
#pragma unroll
  for (int j = 0; j < 64; ++j) refr[j] = 0.0f;

  for (int ec = 0; ec < 4; ++ec) {
    __syncthreads();
    for (int ii = t; ii < 32 * NH; ii += 512) {
      int r = ii >> 7, c = ii & 127;
      sh.pre.wS[r][c] = Wref[(ec * 32 + r) * NH + c];
    }
    for (int ii = t; ii < NS * 32; ii += 512) {
      int r = ii >> 5, c = ii & 31;
      sh.pre.cvS[r][c] = cv[((size_t)b256 + r) * NE + ec * 32 + c];
    }
    __syncthreads();
    for (int hc = 0; hc < 8; ++hc) {
      double a[8] = {0,0,0,0,0,0,0,0};
      for (int e = 0; e < 32; ++e) {
        double cd = (double)sh.pre.cvS[myRow0][e];
        const float* wp = &sh.pre.wS[e][hb + hc * 8];
#pragma unroll
        for (int j = 0; j < 8; ++j) a[j] += cd * (double)wp[j];
      }
#pragma unroll
      for (int j = 0; j < 8; ++j) refr[hc * 8 + j] += (float)a[j];
    }
  }
  __syncthreads();  // pre dead, m live

  // ---------- prologue (m region) ----------
  if (t < NSTEPS) {
    uint32_t o0, o1;
    tf2x32(0u, 42u, 0u, (uint32_t)t, o0, o1);
    sh.m.keyL[t] = make_uint2(o0, o1);
  }
  if (t < NH) {
    sh.m.vvf[t] = vvec[t];
    sh.m.qq[t] = qq0[(size_t)b * NH + t];
  }
  __syncthreads();

  // ---------- 255 decode steps ----------
  for (int step = 0; step < NSTEPS; ++step) {
    const int cur = step & 1;
    const short* rowId_c = cur ? rowIdB : rowIdA;
    const short* pos_c   = cur ? posB   : posA;
    short* rowId_n = cur ? rowIdA : rowIdB;
    short* pos_n   = cur ? posA   : posB;
    const int nA    = nActSh[cur];
    const int jPrev = jSh[cur];
    const bool active = (i < nA);
    const int myRow = active ? (int)rowId_c[i] : 0;

    // adoption: reload refr for the pair that inherited the donor row
    if (jPrev >= 0 && i == jPrev) {
      const float4* rs4 = (const float4*)refScratch;
#pragma unroll
      for (int q = 0; q < 16; ++q) {
        float4 v4 = rs4[halfo * 16 + q];
        refr[4 * q + 0] = v4.x; refr[4 * q + 1] = v4.y;
        refr[4 * q + 2] = v4.z; refr[4 * q + 3] = v4.w;
      }
    }

    // gumbel for (step, myRow) on odd active lanes (overlaps tanh issue)
    float g = 0.0f;
    if (active && halfo) {
      uint2 key = sh.m.keyL[step];
      uint32_t o0, o1;
      tf2x32(key.x, key.y, 0u, (uint32_t)(b256 + myRow), o0, o1);
      uint32_t bits = o0 ^ o1;
      float f = __uint_as_float((bits >> 9) | 0x3f800000u) - 1.0f;
      float u = (f == 0.0f) ? 1.17549435e-38f : f;
      float l1 = -logf(u);
      g = -logf(l1);
    }

    // tanh partial over this thread's 64-wide h-slice
    double accH = 0.0;
    if (active) {
      double a0 = 0, a1 = 0, a2 = 0, a3 = 0;
      const float4* qq4 = (const float4*)(sh.m.qq + hb);
      const float4* vv4 = (const float4*)(sh.m.vvf + hb);
#pragma unroll
      for (int q = 0; q < 16; ++q) {
        float4 qv = qq4[q];
        float4 wv = vv4[q];
        a0 += (double)nr_tanh(qv.x + refr[4 * q + 0]) * (double)wv.x;
        a1 += (double)nr_tanh(qv.y + refr[4 * q + 1]) * (double)wv.y;
        a2 += (double)nr_tanh(qv.z + refr[4 * q + 2]) * (double)wv.z;
        a3 += (double)nr_tanh(qv.w + refr[4 * q + 3]) * (double)wv.w;
      }
      accH = (a0 + a1) + (a2 + a3);
      if (!halfo) sh.m.partA[i] = accH;
    }
    __syncthreads();  // B1

    float val = SENT_NEG; int vRow = 0x7fffffff; float term = 0.0f;
    if (active && halfo) {
      float u_ = (float)(sh.m.partA[i] + accH);   // (low half) + (high half), as r3
      float logit = 10.0f * (float)tanh((double)u_);
      sh.m.logitArr[myRow] = logit;
      term = expf(logit);
      val = logit + g;
      vRow = myRow;
    }
    // full-block reduce: per-wave shfl tree, tie-break lower row id
    {
      float bvv = val; int bR = vRow; float bss = term;
#pragma unroll
      for (int mm = 1; mm <= 32; mm <<= 1) {
        float ov = __shfl_xor(bvv, mm, 64);
        int   oR = __shfl_xor(bR,  mm, 64);
        float os = __shfl_xor(bss, mm, 64);
        bss += os;
        if (ov > bvv || (ov == bvv && oR < bR)) { bvv = ov; bR = oR; }
      }
      if ((t & 63) == 0) {
        int w = t >> 6;
        sh.m.redV[w] = bvv; sh.m.redI[w] = bR; sh.m.redS[w] = bss;
      }
    }
    __syncthreads();  // B2

    // everyone: final argmax over 8 wave partials
    float BV = sh.m.redV[0]; int BR = sh.m.redI[0];
#pragma unroll
    for (int k = 1; k < 8; ++k) {
      float ov = sh.m.redV[k]; int oR = sh.m.redI[k];
      if (ov > BV || (ov == BV && oR < BR)) { BV = ov; BR = oR; }
    }
    if (BR > 255) BR = 0;               // safety (all-masked cannot happen here)
    const int BI = BR;
    const int jj = (int)pos_c[BI];

    if (t == 0) {
      float SS = (sh.m.redS[0] + sh.m.redS[1]) + (sh.m.redS[2] + sh.m.redS[3]);
      SS += (sh.m.redS[4] + sh.m.redS[5]) + (sh.m.redS[6] + sh.m.redS[7]);
      float lp = sh.m.logitArr[BI] - (float)log((double)SS);
      out[(size_t)b * NSTEPS + step] = (float)BI;
      out[(size_t)NBATCH * NSTEPS + (size_t)b * NSTEPS + step] = lp;
      nActSh[cur ^ 1] = nA - 1;
      jSh[cur ^ 1] = (jj < nA - 1) ? jj : -1;
    }

    // compacted list copy into next-parity buffers
    if (t < NS) {
      int donorRow = (int)rowId_c[nA - 1];
      short rid = (t == jj) ? (short)donorRow : rowId_c[t];
      rowId_n[t] = rid;
      if (t < nA - 1) pos_n[rid] = (short)t;
    }
    // donor pair hands its refr slice to the adopter (read next step, post-B4)
    if (jj < nA - 1 && i == nA - 1) {
      float4* rs4 = (float4*)refScratch;
#pragma unroll
      for (int q = 0; q < 16; ++q)
        rs4[halfo * 16 + q] = make_float4(refr[4 * q + 0], refr[4 * q + 1],
                                          refr[4 * q + 2], refr[4 * q + 3]);
    }

    // qq matmul: all 512 threads; h = t>>2, kq = t&3; 32-wide k-partial in f64
    {
      const int h = t >> 2, kq = t & 3;
      const float4* hrow = (const float4*)(cv + ((size_t)(b256 + BI)) * NE + kq * 32);
      float4 hv0 = hrow[0], hv1 = hrow[1], hv2 = hrow[2], hv3 = hrow[3];
      float4 hv4 = hrow[4], hv5 = hrow[5], hv6 = hrow[6], hv7 = hrow[7];

      const float4* m2p = (const float4*)(M2T + (size_t)h * NE + kq * 32);
      double a2 = 0.0;
      {
        float4 m0 = m2p[0], m1 = m2p[1], m2 = m2p[2], m3 = m2p[3];
        float4 m4 = m2p[4], m5 = m2p[5], m6 = m2p[6], m7 = m2p[7];
        a2 += (double)hv0.x*(double)m0.x + (double)hv0.y*(double)m0.y + (double)hv0.z*(double)m0.z + (double)hv0.w*(double)m0.w;
        a2 += (double)hv1.x*(double)m1.x + (double)hv1.y*(double)m1.y + (double)hv1.z*(double)m1.z + (double)hv1.w*(double)m1.w;
        a2 += (double)hv2.x*(double)m2.x + (double)hv2.y*(double)m2.y + (double)hv2.z*(double)m2.z + (double)hv2.w*(double)m2.w;
        a2 += (double)hv3.x*(double)m3.x + (double)hv3.y*(double)m3.y + (double)hv3.z*(double)m3.z + (double)hv3.w*(double)m3.w;
        a2 += (double)hv4.x*(double)m4.x + (double)hv4.y*(double)m4.y + (double)hv4.z*(double)m4.z + (double)hv4.w*(double)m4.w;
        a2 += (double)hv5.x*(double)m5.x + (double)hv5.y*(double)m5.y + (double)hv5.z*(double)m5.z + (double)hv5.w*(double)m5.w;
        a2 += (double)hv6.x*(double)m6.x + (double)hv6.y*(double)m6.y + (double)hv6.z*(double)m6.z + (double)hv6.w*(double)m6.w;
        a2 += (double)hv7.x*(double)m7.x + (double)hv7.y*(double)m7.y + (double)hv7.z*(double)m7.z + (double)hv7.w*(double)m7.w;
      }
      a2 += __shfl_xor(a2, 1, 64);
      a2 += __shfl_xor(a2, 2, 64);

      if (step == 0) {
        const float4* m1p = (const float4*)(M1T + (size_t)h * NE + kq * 32);
        double am = 0.0;
        {
          float4 m0 = m1p[0], m1 = m1p[1], m2 = m1p[2], m3 = m1p[3];
          float4 m4 = m1p[4], m5 = m1p[5], m6 = m1p[6], m7 = m1p[7];
          am += (double)hv0.x*(double)m0.x + (double)hv0.y*(double)m0.y + (double)hv0.z*(double)m0.z + (double)hv0.w*(double)m0.w;
          am += (double)hv1.x*(double)m1.x + (double)hv1.y*(double)m1.y + (double)hv1.z*(double)m1.z + (double)hv1.w*(double)m1.w;
          am += (double)hv2.x*(double)m2.x + (double)hv2.y*(double)m2.y + (double)hv2.z*(double)m2.z + (double)hv2.w*(double)m2.w;
          am += (double)hv3.x*(double)m3.x + (double)hv3.y*(double)m3.y + (double)hv3.z*(double)m3.z + (double)hv3.w*(double)m3.w;
          am += (double)hv4.x*(double)m4.x + (double)hv4.y*(double)m4.y + (double)hv4.z*(double)m4.z + (double)hv4.w*(double)m4.w;
          am += (double)hv5.x*(double)m5.x + (double)hv5.y*(double)m5.y + (double)hv5.z*(double)m5.z + (double)hv5.w*(double)m5.w;
          am += (double)hv6.x*(double)m6.x + (double)hv6.y*(double)m6.y + (double)hv6.z*(double)m6.z + (double)hv6.w*(double)m6.w;
          am += (double)hv7.x*(double)m7.x + (double)hv7.y*(double)m7.y + (double)hv7.z*(double)m7.z + (double)hv7.w*(double)m7.w;
        }
        am += __shfl_xor(am, 1, 64);
        am += __shfl_xor(am, 2, 64);
        if (kq == 0) {
          double dbase = qqbase[(size_t)b * NH + h] + am;
          sh.m.base128[h] = dbase;
          sh.m.qq[h] = (float)(dbase + a2);
        }
      } else if (kq == 0) {
        sh.m.qq[h] = (float)(sh.m.base128[h] + a2);
      }
    }
    __syncthreads();  // B3 (qq + next-step list ready)
  }
}

// ======================= round-2 passing kernel (fallback, unchanged) ==========
__device__ __forceinline__ float fast_tanh_ref(float x) {
  const float Chi = 2.8853900432586670f;
  const float Clo = 3.8519259822379735e-08f;
  float m = fmaf(x, Chi, x * Clo);
  float tt = exp2f(m);
  return 1.0f - 2.0f / (tt + 1.0f);
}

struct MainShR {
  float  query[NE];
  float  qq[NH];
  float  hbar[NE];
  float  inith[NE];
  float  hcur[NE];
  alignas(16) double vvd[NH];
  float  logitArr[NS];
  float  maskArr[NS];
  uint2  keyL[NSTEPS];
  float  meanv[NE];
  float  redV[4];
  int    redI[4];
  double redS[4];
  int    idxSh;
};
struct PreShR {
  float cvS[NS][33];
  float wS[32][NH];
};

__global__ __launch_bounds__(256, 2)
void decoder_kernel_ref(const float* __restrict__ cv, const float* __restrict__ mask_in,
                        const float* __restrict__ liw, const float* __restrict__ Wc,
                        const float* __restrict__ bc, const float* __restrict__ Wv,
                        const float* __restrict__ bv, const float* __restrict__ Wq,
                        const float* __restrict__ Wref, const float* __restrict__ vvec,
                        float* __restrict__ out) {
  const int b = blockIdx.x;
  const int t = threadIdx.x;
  const int b256 = b << 8;
  __shared__ union { PreShR pre; MainShR m; } sh;

  float refr[NH];
#pragma unroll
  for (int h = 0; h < NH; ++h) refr[h] = 0.0f;
  for (int ec = 0; ec < 4; ++ec) {
    const int e0 = ec * 32;
    __syncthreads();
    for (int i = t; i < 32 * NH; i += 256) {
      int r = i >> 7, h = i & 127;
      sh.pre.wS[r][h] = Wref[(e0 + r) * NH + h];
    }
    for (int i = t; i < NS * 32; i += 256) {
      int s2 = i >> 5, j = i & 31;
      sh.pre.cvS[s2][j] = cv[((size_t)b256 + s2) * NE + e0 + j];
    }
    __syncthreads();
#pragma unroll
    for (int hc = 0; hc < 16; ++hc) {
      double a[8] = {0,0,0,0,0,0,0,0};
      for (int e = 0; e < 32; ++e) {
        double cd = (double)sh.pre.cvS[t][e];
#pragma unroll
        for (int j = 0; j < 8; ++j) a[j] += cd * (double)sh.pre.wS[e][hc * 8 + j];
      }
#pragma unroll
      for (int j = 0; j < 8; ++j) refr[hc * 8 + j] += (float)a[j];
    }
  }
  __syncthreads();

  if (t < NSTEPS) {
    uint32_t o0, o1;
    tf2x32(0u, 42u, 0u, (uint32_t)t, o0, o1);
    sh.m.keyL[t] = make_uint2(o0, o1);
  }
  if (t < NH) sh.m.vvd[t] = (double)vvec[t];
  sh.m.maskArr[t] = (mask_in[(size_t)b256 + t] > 0.0f || t == 0) ? 1.0f : 0.0f;
  if (t < NE) {
    double s64 = 0.0;
    for (int s2 = 0; s2 < NS; ++s2) s64 += (double)cv[((size_t)b256 + s2) * NE + t];
    sh.m.meanv[t] = (float)(s64 * (1.0 / 256.0));
  }
  __syncthreads();
  if (t < NE) {
    double acc = 0.0;
    for (int e = 0; e < NE; ++e) acc += (double)sh.m.meanv[e] * (double)Wc[e * NE + t];
    float hbv = (float)acc + bc[t];
    sh.m.hbar[t] = hbv;
    double acc2 = 0.0;
    for (int k = 0; k < 2 * NE; ++k) acc2 += (double)liw[k] * (double)Wv[k * NE + t];
    float r0 = (float)acc2 + bv[t];
    sh.m.query[t] = hbv + r0;
  }
  __syncthreads();

  for (int step = 0; step < NSTEPS; ++step) {
    if (t < NH) {
      double acc = 0.0;
      for (int k = 0; k < NE; ++k) acc += (double)sh.m.query[k] * (double)Wq[k * NH + t];
      sh.m.qq[t] = (float)acc;
    }
    __syncthreads();

    float logit;
    bool masked = (sh.m.maskArr[t] != 0.0f);
    if (!masked) {
      double a0 = 0.0, a1 = 0.0, a2 = 0.0, a3 = 0.0;
      const float4*  qq4 = (const float4*)sh.m.qq;
      const double2* vv2 = (const double2*)sh.m.vvd;
#pragma unroll
      for (int h4 = 0; h4 < 32; ++h4) {
        float4  q  = qq4[h4];
        double2 va = vv2[2 * h4];
        double2 vb = vv2[2 * h4 + 1];
        a0 += (double)fast_tanh_ref(q.x + refr[4 * h4 + 0]) * va.x;
        a1 += (double)fast_tanh_ref(q.y + refr[4 * h4 + 1]) * va.y;
        a2 += (double)fast_tanh_ref(q.z + refr[4 * h4 + 2]) * vb.x;
        a3 += (double)fast_tanh_ref(q.w + refr[4 * h4 + 3]) * vb.y;
      }
      float u_ = (float)((a0 + a1) + (a2 + a3));
      logit = 10.0f * (float)tanh((double)u_);
    } else {
      logit = NEGINF;
    }
    sh.m.logitArr[t] = logit;

    uint2 key = sh.m.keyL[step];
    uint32_t j = (uint32_t)(b256 + t);
    uint32_t o0, o1;
    tf2x32(key.x, key.y, 0u, j, o0, o1);
    uint32_t bits = o0 ^ o1;
    float f = __uint_as_float((bits >> 9) | 0x3f800000u) - 1.0f;
    float u = (f == 0.0f) ? 1.17549435e-38f : f;
    float l1 = (float)(-log((double)u));
    float g  = (float)(-log((double)l1));
    float val = logit + g;
    double term = exp((double)logit);

    float bv_ = val; int bi = t; double bs = term;
#pragma unroll
    for (int m = 1; m <= 32; m <<= 1) {
      float  ov = __shfl_xor(bv_, m, 64);
      int    oi = __shfl_xor(bi,  m, 64);
      double os = __shfl_xor(bs,  m, 64);
      if (ov > bv_ || (ov == bv_ && oi < bi)) { bv_ = ov; bi = oi; }
      bs += os;
    }
    int w = t >> 6;
    if ((t & 63) == 0) { sh.m.redV[w] = bv_; sh.m.redI[w] = bi; sh.m.redS[w] = bs; }
    __syncthreads();

    if (t == 0) {
      float BV = sh.m.redV[0]; int BI = sh.m.redI[0];
      for (int k = 1; k < 4; ++k) {
        float ov = sh.m.redV[k]; int oi = sh.m.redI[k];
        if (ov > BV || (ov == BV && oi < BI)) { BV = ov; BI = oi; }
      }
      double SS = ((sh.m.redS[0] + sh.m.redS[1]) + (sh.m.redS[2] + sh.m.redS[3]));
      sh.m.idxSh = BI;
      float lp = sh.m.logitArr[BI] - (float)log(SS);
      out[(size_t)b * NSTEPS + step] = (float)BI;
      out[(size_t)NBATCH * NSTEPS + (size_t)b * NSTEPS + step] = lp;
    }
    __syncthreads();

    int idx = sh.m.idxSh;
    if (t == idx) sh.m.maskArr[t] = 1.0f;
    if (t < NE) {
      float hc = cv[((size_t)b256 + idx) * NE + t];
      sh.m.hcur[t] = hc;
      if (step == 0) sh.m.inith[t] = hc;
    }
    __syncthreads();

    if (t < NE) {
      double acc2 = 0.0;
      for (int k = 0; k < NE; ++k) acc2 += (double)sh.m.inith[k] * (double)Wv[k * NE + t];
      for (int k = 0; k < NE; ++k) acc2 += (double)sh.m.hcur[k] * (double)Wv[(NE + k) * NE + t];
      float mm = (float)acc2 + bv[t];
      sh.m.query[t] = sh.m.hbar[t] + mm;
    }
    __syncthreads();
  }
}

extern "C" void kernel_launch(void* const* d_in, const int* in_sizes, int n_in,
                              void* d_out, int out_size, void* d_ws, size_t ws_size,
                              hipStream_t stream) {
  const float* cv   = (const float*)d_in[0];
  const float* mask = (const float*)d_in[2];
  const float* liw  = (const float*)d_in[3];
  const float* Wc   = (const float*)d_in[4];
  const float* bc   = (const float*)d_in[5];
  const float* Wv   = (const float*)d_in[6];
  const float* bv   = (const float*)d_in[7];
  const float* Wq   = (const float*)d_in[8];
  const float* Wref = (const float*)d_in[9];
  const float* vv   = (const float*)d_in[10];
  (void)in_sizes; (void)n_in; (void)out_size;

  const size_t SZ_QQB = (size_t)NBATCH * NH * sizeof(double);  // 512 KB
  const size_t SZ_M   = (size_t)NE * NH * sizeof(float);       // 64 KB each
  const size_t SZ_QQ0 = (size_t)NBATCH * NH * sizeof(float);   // 256 KB
  const size_t need = SZ_QQB + 2 * SZ_M + SZ_QQ0 + 512;

  if (ws_size >= need) {
    char* p = (char*)d_ws;
    double* qqbase = (double*)p;            p += SZ_QQB;
    float*  M1T    = (float*)p;             p += SZ_M;
    float*  M2T    = (float*)p;             p += SZ_M;
    float*  qq0    = (float*)p;             p += SZ_QQ0;
    float*  rest0  = (float*)p;

    k1_mats<<<257, 128, 0, stream>>>(Wv, Wq, liw, bv, M1T, M2T, rest0);
    k2_base<<<NBATCH, 128, 0, stream>>>(cv, Wc, bc, bv, Wq, rest0, qqbase, qq0);
    decode_main<<<NBATCH, 512, 0, stream>>>(cv, mask, Wref, vv, qqbase, M1T, M2T,
                                            qq0, (float*)d_out);
  } else {
    decoder_kernel_ref<<<NBATCH, 256, 0, stream>>>(cv, mask, liw, Wc, bc, Wv, bv,
                                                   Wq, Wref, vv, (float*)d_out);
  }
}

// Round 5
// 6897.438 us; speedup vs baseline: 1.0389x; 1.0389x over previous
//
#include <hip/hip_runtime.h>
#include <hip/hip_bf16.h>
#include <stdint.h>
#include <math.h>

#define NBATCH 512
#define NS 256
#define NE 128
#define NH 128
#define NSTEPS 255
#define NEGINF -1e8f
#define SENT_NEG -1e30f

// ---------------- threefry2x32 (partitionable path, verified r2/r3) ----------------
__device__ __forceinline__ uint32_t rotl32(uint32_t x, uint32_t r) {
  return (x << r) | (x >> (32u - r));
}

__device__ __forceinline__ void tf2x32(uint32_t k0, uint32_t k1,
                                       uint32_t x0, uint32_t x1,
                                       uint32_t& o0, uint32_t& o1) {
  uint32_t ks2 = k0 ^ k1 ^ 0x1BD11BDAu;
  x0 += k0; x1 += k1;
#define TF_R4(a,b,c,d) \
  x0 += x1; x1 = rotl32(x1,a); x1 ^= x0; \
  x0 += x1; x1 = rotl32(x1,b); x1 ^= x0; \
  x0 += x1; x1 = rotl32(x1,c); x1 ^= x0; \
  x0 += x1; x1 = rotl32(x1,d); x1 ^= x0;
  TF_R4(13,15,26,6)   x0 += k1;  x1 += ks2 + 1u;
  TF_R4(17,29,16,24)  x0 += ks2; x1 += k0 + 2u;
  TF_R4(13,15,26,6)   x0 += k0;  x1 += k1 + 3u;
  TF_R4(17,29,16,24)  x0 += k1;  x1 += ks2 + 4u;
  TF_R4(13,15,26,6)   x0 += ks2; x1 += k0 + 5u;
#undef TF_R4
  o0 = x0; o1 = x1;
}

// tanh via hw exp2 + rcp + 1 Newton step: <=1 ulp (verified exact-index r3/r4)
__device__ __forceinline__ float nr_tanh(float x) {
  const float Chi = 2.8853900432586670f;      // float(2*log2(e))
  const float Clo = 3.8519259822379735e-08f;  // residual
  float m = fmaf(x, Chi, x * Clo);
  m = fminf(m, 126.0f);
  float tt = __builtin_amdgcn_exp2f(m);
  float d  = tt + 1.0f;
  float r  = __builtin_amdgcn_rcpf(d);
  r = r * fmaf(-d, r, 2.0f);
  return fmaf(-2.0f, r, 1.0f);
}

// ======================= precompute kernels (unchanged) =======================
__global__ void k1_mats(const float* __restrict__ Wv, const float* __restrict__ Wq,
                        const float* __restrict__ liw, const float* __restrict__ bvv,
                        float* __restrict__ M1T, float* __restrict__ M2T,
                        float* __restrict__ rest0) {
  int e = blockIdx.x, h = threadIdx.x;
  __shared__ float wrow[NE];
  if (e < 256) {
    wrow[h] = Wv[e * NE + h];
    __syncthreads();
    double a = 0.0;
    for (int k = 0; k < NE; ++k) a += (double)wrow[k] * (double)Wq[k * NH + h];
    if (e < 128) M1T[h * NE + e] = (float)a;
    else         M2T[h * NE + (e - 128)] = (float)a;
  } else {
    double a = 0.0;
    for (int k = 0; k < 2 * NE; ++k) a += (double)liw[k] * (double)Wv[k * NE + h];
    rest0[h] = (float)a + bvv[h];
  }
}

__global__ void k2_base(const float* __restrict__ cv, const float* __restrict__ Wc,
                        const float* __restrict__ bc, const float* __restrict__ bvv,
                        const float* __restrict__ Wq, const float* __restrict__ rest0,
                        double* __restrict__ qqbase, float* __restrict__ qq0) {
  int b = blockIdx.x, h = threadIdx.x;
  int b256 = b << 8;
  __shared__ float meanL[NE], hbarL[NE];
  double ms = 0.0;
  for (int s = 0; s < NS; ++s) ms += (double)cv[((size_t)b256 + s) * NE + h];
  meanL[h] = (float)(ms * (1.0 / 256.0));
  __syncthreads();
  double a = 0.0;
  for (int e = 0; e < NE; ++e) a += (double)meanL[e] * (double)Wc[e * NE + h];
  hbarL[h] = (float)a + bc[h];
  __syncthreads();
  double ab = 0.0, a0 = 0.0;
  for (int k = 0; k < NE; ++k) {
    double w = (double)Wq[k * NH + h];
    ab += (double)(hbarL[k] + bvv[k]) * w;
    a0 += (double)(hbarL[k] + rest0[k]) * w;
  }
  qqbase[(size_t)b * NH + h] = ab;
  qq0[(size_t)b * NH + h] = (float)a0;
}

// ======================= main decode kernel =======================
struct MainSh {
  alignas(16) float  qq[NH];
  alignas(16) float  vvf[NH];
  alignas(8)  double partA[NS];     // indexed by list position i
  float  logitArr[NS];              // indexed by ROW id
  alignas(8)  double base128[NH];
  uint2  keyL[NSTEPS];
  float  redV[8];
  float  redS[8];
  int    redI[8];
};

struct PreSh {
  float cvS[NS][33];
  float wS[32][NH];
};

__global__ __launch_bounds__(512, 4)
void decode_main(const float* __restrict__ cv,
                 const float* __restrict__ mask_in,
                 const float* __restrict__ Wref,
                 const float* __restrict__ vvec,
                 const double* __restrict__ qqbase,
                 const float* __restrict__ M1T,
                 const float* __restrict__ M2T,
                 const float* __restrict__ qq0,
                 float* __restrict__ out) {
  const int b = blockIdx.x;
  const int t = threadIdx.x;
  const int b256 = b << 8;
  const int i = t & 255;          // list position (r3 layout: conflict-free)
  const int halfo = t >> 8;       // 0: h[0..63], 1: h[64..127]
  const int hb = halfo << 6;

  __shared__ union { PreSh pre; MainSh m; } sh;
  // persistent: compaction state, double-buffered by step parity
  __shared__ short rowIdA[NS], rowIdB[NS], posA[NS], posB[NS];
  __shared__ int nActSh[2], jSh[2], tmp8[4];
  __shared__ alignas(16) float refScratch[NE];

  // ---------- build initial active-row list ----------
  bool act0 = false;
  if (t < NS) {
    act0 = !((t == 0) || (mask_in[(size_t)b256 + t] > 0.0f));
    uint64_t mb = __ballot(act0);
    int lane = t & 63, w = t >> 6;
    int pre = __popcll(mb & (((uint64_t)1 << lane) - 1));
    if (lane == 0) tmp8[w] = (int)__popcll(mb);
    posA[t] = (short)pre;
  }
  __syncthreads();
  if (t < NS) {
    int base = 0;
    for (int k = 0; k < (t >> 6); ++k) base += tmp8[k];
    int p = base + (int)posA[t];
    if (act0) rowIdA[p] = (short)t;
    posA[t] = (short)p;
  }
  if (t == 0) {
    nActSh[0] = tmp8[0] + tmp8[1] + tmp8[2] + tmp8[3];
    jSh[0] = -1;
  }
  __syncthreads();
  const int nAct0 = nActSh[0];

  // ---------- Phase 1: refr[j] = ref[myRow0][hb+j] (bit-identical chunking) ----------
  const int myRow0 = (i < nAct0) ? (int)rowIdA[i] : 0;
  float refr[64];
#pragma unroll
  for (int j = 0; j < 64; ++j) refr[j] = 0.0f;

  for (int ec = 0; ec < 4; ++ec) {
    __syncthreads();
    for (int ii = t; ii < 32 * NH; ii += 512) {
      int r = ii >> 7, c = ii & 127;
      sh.pre.wS[r][c] = Wref[(ec * 32 + r) * NH + c];
    }
    for (int ii = t; ii < NS * 32; ii += 512) {
      int r = ii >> 5, c = ii & 31;
      sh.pre.cvS[r][c] = cv[((size_t)b256 + r) * NE + ec * 32 + c];
    }
    __syncthreads();
    for (int hc = 0; hc < 8; ++hc) {
      double a[8] = {0,0,0,0,0,0,0,0};
      for (int e = 0; e < 32; ++e) {
        double cd = (double)sh.pre.cvS[myRow0][e];
        const float* wp = &sh.pre.wS[e][hb + hc * 8];
#pragma unroll
        for (int j = 0; j < 8; ++j) a[j] += cd * (double)wp[j];
      }
#pragma unroll
      for (int j = 0; j < 8; ++j) refr[hc * 8 + j] += (float)a[j];
    }
  }
  __syncthreads();  // pre dead, m live

  // ---------- prologue ----------
  if (t < NSTEPS) {
    uint32_t o0, o1;
    tf2x32(0u, 42u, 0u, (uint32_t)t, o0, o1);
    sh.m.keyL[t] = make_uint2(o0, o1);
  }
  if (t < NH) {
    sh.m.vvf[t] = vvec[t];
    sh.m.qq[t] = qq0[(size_t)b * NH + t];
  }
  // M2T resident in registers: thread t holds M2T[t>>2][(t&3)*32 .. +32)
  const int hq = t >> 2, kq = t & 3;
  float4 m2r[8];
  {
    const float4* m2p = (const float4*)(M2T + (size_t)hq * NE + kq * 32);
#pragma unroll
    for (int q = 0; q < 8; ++q) m2r[q] = m2p[q];
  }
  __syncthreads();

  // ---------- 255 decode steps ----------
  for (int step = 0; step < NSTEPS; ++step) {
    const int cur = step & 1;
    const short* rowId_c = cur ? rowIdB : rowIdA;
    const short* pos_c   = cur ? posB   : posA;
    short* rowId_n = cur ? rowIdA : rowIdB;
    short* pos_n   = cur ? posA   : posB;
    const int nA    = nActSh[cur];
    const int jPrev = jSh[cur];
    const bool active = (i < nA);
    const int myRow = active ? (int)rowId_c[i] : 0;

    // adoption: the pair that inherited the donor row reloads its refr slice
    if (jPrev >= 0 && i == jPrev) {
      const float4* rs4 = (const float4*)(refScratch + hb);
#pragma unroll
      for (int q = 0; q < 16; ++q) {
        float4 v4 = rs4[q];
        refr[4 * q + 0] = v4.x; refr[4 * q + 1] = v4.y;
        refr[4 * q + 2] = v4.z; refr[4 * q + 3] = v4.w;
      }
    }

    // gumbel for (step, myRow) on upper active threads
    float g = 0.0f;
    if (halfo && active) {
      uint2 key = sh.m.keyL[step];
      uint32_t o0, o1;
      tf2x32(key.x, key.y, 0u, (uint32_t)(b256 + myRow), o0, o1);
      uint32_t bits = o0 ^ o1;
      float f = __uint_as_float((bits >> 9) | 0x3f800000u) - 1.0f;
      float u = (f == 0.0f) ? 1.17549435e-38f : f;
      float l1 = -logf(u);
      g = -logf(l1);
    }

    // tanh partial over this thread's 64-wide h-slice (wave-uniform LDS reads)
    double accH = 0.0;
    if (active) {
      double a0 = 0, a1 = 0, a2 = 0, a3 = 0;
      const float4* qq4 = (const float4*)(sh.m.qq + hb);
      const float4* vv4 = (const float4*)(sh.m.vvf + hb);
#pragma unroll
      for (int q = 0; q < 16; ++q) {
        float4 qv = qq4[q];
        float4 wv = vv4[q];
        a0 += (double)nr_tanh(qv.x + refr[4 * q + 0]) * (double)wv.x;
        a1 += (double)nr_tanh(qv.y + refr[4 * q + 1]) * (double)wv.y;
        a2 += (double)nr_tanh(qv.z + refr[4 * q + 2]) * (double)wv.z;
        a3 += (double)nr_tanh(qv.w + refr[4 * q + 3]) * (double)wv.w;
      }
      accH = (a0 + a1) + (a2 + a3);
      if (!halfo) sh.m.partA[i] = accH;
    }
    __syncthreads();  // B1

    if (halfo) {
      float val = SENT_NEG; int vRow = 0x7fffffff; float term = 0.0f;
      if (active) {
        float u_ = (float)(sh.m.partA[i] + accH);   // lower + upper, as r3
        float logit = 10.0f * (float)tanh((double)u_);
        sh.m.logitArr[myRow] = logit;
        term = expf(logit);
        val = logit + g;
        vRow = myRow;
      }
      float bvv = val; int bR = vRow; float bss = term;
#pragma unroll
      for (int mm = 1; mm <= 32; mm <<= 1) {
        float ov = __shfl_xor(bvv, mm, 64);
        int   oR = __shfl_xor(bR,  mm, 64);
        float os = __shfl_xor(bss, mm, 64);
        bss += os;
        if (ov > bvv || (ov == bvv && oR < bR)) { bvv = ov; bR = oR; }
      }
      if ((t & 63) == 0) {
        int w = t >> 6;   // 4..7
        sh.m.redV[w] = bvv; sh.m.redI[w] = bR; sh.m.redS[w] = bss;
      }
    }
    __syncthreads();  // B2

    // final argmax over the 4 upper-wave partials (all threads)
    float BV = sh.m.redV[4]; int BR = sh.m.redI[4];
#pragma unroll
    for (int k = 5; k < 8; ++k) {
      float ov = sh.m.redV[k]; int oR = sh.m.redI[k];
      if (ov > BV || (ov == BV && oR < BR)) { BV = ov; BR = oR; }
    }
    if ((unsigned)BR > 255u) BR = 0;   // safety
    const int BI = BR;
    const int jj = (int)pos_c[BI];

    if (t == 0) {
      float SS = (sh.m.redS[4] + sh.m.redS[5]) + (sh.m.redS[6] + sh.m.redS[7]);
      float lp = sh.m.logitArr[BI] - (float)log((double)SS);
      out[(size_t)b * NSTEPS + step] = (float)BI;
      out[(size_t)NBATCH * NSTEPS + (size_t)b * NSTEPS + step] = lp;
      nActSh[cur ^ 1] = nA - 1;
      jSh[cur ^ 1] = (jj < nA - 1) ? jj : -1;
    }

    // compacted list copy into next-parity buffers
    if (t < NS) {
      int donorRow = (int)rowId_c[nA - 1];
      short rid = (t == jj) ? (short)donorRow : rowId_c[t];
      rowId_n[t] = rid;
      if (t < nA - 1) pos_n[rid] = (short)t;
    }
    // donor pair hands its refr slice to the adopter (read next step, post-B3)
    if (jj < nA - 1 && i == nA - 1) {
      float4* rs4 = (float4*)(refScratch + hb);
#pragma unroll
      for (int q = 0; q < 16; ++q)
        rs4[q] = make_float4(refr[4 * q + 0], refr[4 * q + 1],
                             refr[4 * q + 2], refr[4 * q + 3]);
    }

    // qq update: h = t>>2, kq = t&3; M2T from registers; only cv row from global
    if (step + 1 < NSTEPS) {
      const float4* hrow = (const float4*)(cv + (size_t)(b256 + BI) * NE + kq * 32);
      float4 hv0 = hrow[0], hv1 = hrow[1], hv2 = hrow[2], hv3 = hrow[3];
      float4 hv4 = hrow[4], hv5 = hrow[5], hv6 = hrow[6], hv7 = hrow[7];

      double a2 = 0.0;
      a2 += (double)hv0.x*(double)m2r[0].x + (double)hv0.y*(double)m2r[0].y + (double)hv0.z*(double)m2r[0].z + (double)hv0.w*(double)m2r[0].w;
      a2 += (double)hv1.x*(double)m2r[1].x + (double)hv1.y*(double)m2r[1].y + (double)hv1.z*(double)m2r[1].z + (double)hv1.w*(double)m2r[1].w;
      a2 += (double)hv2.x*(double)m2r[2].x + (double)hv2.y*(double)m2r[2].y + (double)hv2.z*(double)m2r[2].z + (double)hv2.w*(double)m2r[2].w;
      a2 += (double)hv3.x*(double)m2r[3].x + (double)hv3.y*(double)m2r[3].y + (double)hv3.z*(double)m2r[3].z + (double)hv3.w*(double)m2r[3].w;
      a2 += (double)hv4.x*(double)m2r[4].x + (double)hv4.y*(double)m2r[4].y + (double)hv4.z*(double)m2r[4].z + (double)hv4.w*(double)m2r[4].w;
      a2 += (double)hv5.x*(double)m2r[5].x + (double)hv5.y*(double)m2r[5].y + (double)hv5.z*(double)m2r[5].z + (double)hv5.w*(double)m2r[5].w;
      a2 += (double)hv6.x*(double)m2r[6].x + (double)hv6.y*(double)m2r[6].y + (double)hv6.z*(double)m2r[6].z + (double)hv6.w*(double)m2r[6].w;
      a2 += (double)hv7.x*(double)m2r[7].x + (double)hv7.y*(double)m2r[7].y + (double)hv7.z*(double)m2r[7].z + (double)hv7.w*(double)m2r[7].w;
      a2 += __shfl_xor(a2, 1, 64);
      a2 += __shfl_xor(a2, 2, 64);

      if (step == 0) {
        const float4* m1p = (const float4*)(M1T + (size_t)hq * NE + kq * 32);
        double am = 0.0;
        {
          float4 m0 = m1p[0], m1 = m1p[1], m2 = m1p[2], m3 = m1p[3];
          float4 m4 = m1p[4], m5 = m1p[5], m6 = m1p[6], m7 = m1p[7];
          am += (double)hv0.x*(double)m0.x + (double)hv0.y*(double)m0.y + (double)hv0.z*(double)m0.z + (double)hv0.w*(double)m0.w;
          am += (double)hv1.x*(double)m1.x + (double)hv1.y*(double)m1.y + (double)hv1.z*(double)m1.z + (double)hv1.w*(double)m1.w;
          am += (double)hv2.x*(double)m2.x + (double)hv2.y*(double)m2.y + (double)hv2.z*(double)m2.z + (double)hv2.w*(double)m2.w;
          am += (double)hv3.x*(double)m3.x + (double)hv3.y*(double)m3.y + (double)hv3.z*(double)m3.z + (double)hv3.w*(double)m3.w;
          am += (double)hv4.x*(double)m4.x + (double)hv4.y*(double)m4.y + (double)hv4.z*(double)m4.z + (double)hv4.w*(double)m4.w;
          am += (double)hv5.x*(double)m5.x + (double)hv5.y*(double)m5.y + (double)hv5.z*(double)m5.z + (double)hv5.w*(double)m5.w;
          am += (double)hv6.x*(double)m6.x + (double)hv6.y*(double)m6.y + (double)hv6.z*(double)m6.z + (double)hv6.w*(double)m6.w;
          am += (double)hv7.x*(double)m7.x + (double)hv7.y*(double)m7.y + (double)hv7.z*(double)m7.z + (double)hv7.w*(double)m7.w;
        }
        am += __shfl_xor(am, 1, 64);
        am += __shfl_xor(am, 2, 64);
        if (kq == 0) {
          double dbase = qqbase[(size_t)b * NH + hq] + am;
          sh.m.base128[hq] = dbase;
          sh.m.qq[hq] = (float)(dbase + a2);
        }
      } else if (kq == 0) {
        sh.m.qq[hq] = (float)(sh.m.base128[hq] + a2);
      }
    }
    __syncthreads();  // B3
  }
}

// ======================= round-2 passing kernel (fallback, unchanged) ==========
__device__ __forceinline__ float fast_tanh_ref(float x) {
  const float Chi = 2.8853900432586670f;
  const float Clo = 3.8519259822379735e-08f;
  float m = fmaf(x, Chi, x * Clo);
  float tt = exp2f(m);
  return 1.0f - 2.0f / (tt + 1.0f);
}

struct MainShR {
  float  query[NE];
  float  qq[NH];
  float  hbar[NE];
  float  inith[NE];
  float  hcur[NE];
  alignas(16) double vvd[NH];
  float  logitArr[NS];
  float  maskArr[NS];
  uint2  keyL[NSTEPS];
  float  meanv[NE];
  float  redV[4];
  int    redI[4];
  double redS[4];
  int    idxSh;
};
struct PreShR {
  float cvS[NS][33];
  float wS[32][NH];
};

__global__ __launch_bounds__(256, 2)
void decoder_kernel_ref(const float* __restrict__ cv, const float* __restrict__ mask_in,
                        const float* __restrict__ liw, const float* __restrict__ Wc,
                        const float* __restrict__ bc, const float* __restrict__ Wv,
                        const float* __restrict__ bv, const float* __restrict__ Wq,
                        const float* __restrict__ Wref, const float* __restrict__ vvec,
                        float* __restrict__ out) {
  const int b = blockIdx.x;
  const int t = threadIdx.x;
  const int b256 = b << 8;
  __shared__ union { PreShR pre; MainShR m; } sh;

  float refr[NH];
#pragma unroll
  for (int h = 0; h < NH; ++h) refr[h] = 0.0f;
  for (int ec = 0; ec < 4; ++ec) {
    const int e0 = ec * 32;
    __syncthreads();
    for (int i = t; i < 32 * NH; i += 256) {
      int r = i >> 7, h = i & 127;
      sh.pre.wS[r][h] = Wref[(e0 + r) * NH + h];
    }
    for (int i = t; i < NS * 32; i += 256) {
      int s2 = i >> 5, j = i & 31;
      sh.pre.cvS[s2][j] = cv[((size_t)b256 + s2) * NE + e0 + j];
    }
    __syncthreads();
#pragma unroll
    for (int hc = 0; hc < 16; ++hc) {
      double a[8] = {0,0,0,0,0,0,0,0};
      for (int e = 0; e < 32; ++e) {
        double cd = (double)sh.pre.cvS[t][e];
#pragma unroll
        for (int j = 0; j < 8; ++j) a[j] += cd * (double)sh.pre.wS[e][hc * 8 + j];
      }
#pragma unroll
      for (int j = 0; j < 8; ++j) refr[hc * 8 + j] += (float)a[j];
    }
  }
  __syncthreads();

  if (t < NSTEPS) {
    uint32_t o0, o1;
    tf2x32(0u, 42u, 0u, (uint32_t)t, o0, o1);
    sh.m.keyL[t] = make_uint2(o0, o1);
  }
  if (t < NH) sh.m.vvd[t] = (double)vvec[t];
  sh.m.maskArr[t] = (mask_in[(size_t)b256 + t] > 0.0f || t == 0) ? 1.0f : 0.0f;
  if (t < NE) {
    double s64 = 0.0;
    for (int s2 = 0; s2 < NS; ++s2) s64 += (double)cv[((size_t)b256 + s2) * NE + t];
    sh.m.meanv[t] = (float)(s64 * (1.0 / 256.0));
  }
  __syncthreads();
  if (t < NE) {
    double acc = 0.0;
    for (int e = 0; e < NE; ++e) acc += (double)sh.m.meanv[e] * (double)Wc[e * NE + t];
    float hbv = (float)acc + bc[t];
    sh.m.hbar[t] = hbv;
    double acc2 = 0.0;
    for (int k = 0; k < 2 * NE; ++k) acc2 += (double)liw[k] * (double)Wv[k * NE + t];
    float r0 = (float)acc2 + bv[t];
    sh.m.query[t] = hbv + r0;
  }
  __syncthreads();

  for (int step = 0; step < NSTEPS; ++step) {
    if (t < NH) {
      double acc = 0.0;
      for (int k = 0; k < NE; ++k) acc += (double)sh.m.query[k] * (double)Wq[k * NH + t];
      sh.m.qq[t] = (float)acc;
    }
    __syncthreads();

    float logit;
    bool masked = (sh.m.maskArr[t] != 0.0f);
    if (!masked) {
      double a0 = 0.0, a1 = 0.0, a2 = 0.0, a3 = 0.0;
      const float4*  qq4 = (const float4*)sh.m.qq;
      const double2* vv2 = (const double2*)sh.m.vvd;
#pragma unroll
      for (int h4 = 0; h4 < 32; ++h4) {
        float4  q  = qq4[h4];
        double2 va = vv2[2 * h4];
        double2 vb = vv2[2 * h4 + 1];
        a0 += (double)fast_tanh_ref(q.x + refr[4 * h4 + 0]) * va.x;
        a1 += (double)fast_tanh_ref(q.y + refr[4 * h4 + 1]) * va.y;
        a2 += (double)fast_tanh_ref(q.z + refr[4 * h4 + 2]) * vb.x;
        a3 += (double)fast_tanh_ref(q.w + refr[4 * h4 + 3]) * vb.y;
      }
      float u_ = (float)((a0 + a1) + (a2 + a3));
      logit = 10.0f * (float)tanh((double)u_);
    } else {
      logit = NEGINF;
    }
    sh.m.logitArr[t] = logit;

    uint2 key = sh.m.keyL[step];
    uint32_t j = (uint32_t)(b256 + t);
    uint32_t o0, o1;
    tf2x32(key.x, key.y, 0u, j, o0, o1);
    uint32_t bits = o0 ^ o1;
    float f = __uint_as_float((bits >> 9) | 0x3f800000u) - 1.0f;
    float u = (f == 0.0f) ? 1.17549435e-38f : f;
    float l1 = (float)(-log((double)u));
    float g  = (float)(-log((double)l1));
    float val = logit + g;
    double term = exp((double)logit);

    float bv_ = val; int bi = t; double bs = term;
#pragma unroll
    for (int m = 1; m <= 32; m <<= 1) {
      float  ov = __shfl_xor(bv_, m, 64);
      int    oi = __shfl_xor(bi,  m, 64);
      double os = __shfl_xor(bs,  m, 64);
      if (ov > bv_ || (ov == bv_ && oi < bi)) { bv_ = ov; bi = oi; }
      bs += os;
    }
    int w = t >> 6;
    if ((t & 63) == 0) { sh.m.redV[w] = bv_; sh.m.redI[w] = bi; sh.m.redS[w] = bs; }
    __syncthreads();

    if (t == 0) {
      float BV = sh.m.redV[0]; int BI = sh.m.redI[0];
      for (int k = 1; k < 4; ++k) {
        float ov = sh.m.redV[k]; int oi = sh.m.redI[k];
        if (ov > BV || (ov == BV && oi < BI)) { BV = ov; BI = oi; }
      }
      double SS = ((sh.m.redS[0] + sh.m.redS[1]) + (sh.m.redS[2] + sh.m.redS[3]));
      sh.m.idxSh = BI;
      float lp = sh.m.logitArr[BI] - (float)log(SS);
      out[(size_t)b * NSTEPS + step] = (float)BI;
      out[(size_t)NBATCH * NSTEPS + (size_t)b * NSTEPS + step] = lp;
    }
    __syncthreads();

    int idx = sh.m.idxSh;
    if (t == idx) sh.m.maskArr[t] = 1.0f;
    if (t < NE) {
      float hc = cv[((size_t)b256 + idx) * NE + t];
      sh.m.hcur[t] = hc;
      if (step == 0) sh.m.inith[t] = hc;
    }
    __syncthreads();

    if (t < NE) {
      double acc2 = 0.0;
      for (int k = 0; k < NE; ++k) acc2 += (double)sh.m.inith[k] * (double)Wv[k * NE + t];
      for (int k = 0; k < NE; ++k) acc2 += (double)sh.m.hcur[k] * (double)Wv[(NE + k) * NE + t];
      float mm = (float)acc2 + bv[t];
      sh.m.query[t] = sh.m.hbar[t] + mm;
    }
    __syncthreads();
  }
}

extern "C" void kernel_launch(void* const* d_in, const int* in_sizes, int n_in,
                              void* d_out, int out_size, void* d_ws, size_t ws_size,
                              hipStream_t stream) {
  const float* cv   = (const float*)d_in[0];
  const float* mask = (const float*)d_in[2];
  const float* liw  = (const float*)d_in[3];
  const float* Wc   = (const float*)d_in[4];
  const float* bc   = (const float*)d_in[5];
  const float* Wv   = (const float*)d_in[6];
  const float* bv   = (const float*)d_in[7];
  const float* Wq   = (const float*)d_in[8];
  const float* Wref = (const float*)d_in[9];
  const float* vv   = (const float*)d_in[10];
  (void)in_sizes; (void)n_in; (void)out_size;

  const size_t SZ_QQB = (size_t)NBATCH * NH * sizeof(double);  // 512 KB
  const size_t SZ_M   = (size_t)NE * NH * sizeof(float);       // 64 KB each
  const size_t SZ_QQ0 = (size_t)NBATCH * NH * sizeof(float);   // 256 KB
  const size_t need = SZ_QQB + 2 * SZ_M + SZ_QQ0 + 512;

  if (ws_size >= need) {
    char* p = (char*)d_ws;
    double* qqbase = (double*)p;            p += SZ_QQB;
    float*  M1T    = (float*)p;             p += SZ_M;
    float*  M2T    = (float*)p;             p += SZ_M;
    float*  qq0    = (float*)p;             p += SZ_QQ0;
    float*  rest0  = (float*)p;

    k1_mats<<<257, 128, 0, stream>>>(Wv, Wq, liw, bv, M1T, M2T, rest0);
    k2_base<<<NBATCH, 128, 0, stream>>>(cv, Wc, bc, bv, Wq, rest0, qqbase, qq0);
    decode_main<<<NBATCH, 512, 0, stream>>>(cv, mask, Wref, vv, qqbase, M1T, M2T,
                                            qq0, (float*)d_out);
  } else {
    decoder_kernel_ref<<<NBATCH, 256, 0, stream>>>(cv, mask, liw, Wc, bc, Wv, bv,
                                                   Wq, Wref, vv, (float*)d_out);
  }
}

// Round 6
// 4728.415 us; speedup vs baseline: 1.5155x; 1.4587x over previous
//
#include <hip/hip_runtime.h>
#include <hip/hip_bf16.h>
#include <stdint.h>
#include <math.h>

#define NBATCH 512
#define NS 256
#define NE 128
#define NH 128
#define NSTEPS 255
#define NEGINF -1e8f
#define SENT_NEG -1e30f

// ---------------- threefry2x32 (partitionable path, verified r2/r3/r5) ----------------
__device__ __forceinline__ uint32_t rotl32(uint32_t x, uint32_t r) {
  return (x << r) | (x >> (32u - r));
}

__device__ __forceinline__ void tf2x32(uint32_t k0, uint32_t k1,
                                       uint32_t x0, uint32_t x1,
                                       uint32_t& o0, uint32_t& o1) {
  uint32_t ks2 = k0 ^ k1 ^ 0x1BD11BDAu;
  x0 += k0; x1 += k1;
#define TF_R4(a,b,c,d) \
  x0 += x1; x1 = rotl32(x1,a); x1 ^= x0; \
  x0 += x1; x1 = rotl32(x1,b); x1 ^= x0; \
  x0 += x1; x1 = rotl32(x1,c); x1 ^= x0; \
  x0 += x1; x1 = rotl32(x1,d); x1 ^= x0;
  TF_R4(13,15,26,6)   x0 += k1;  x1 += ks2 + 1u;
  TF_R4(17,29,16,24)  x0 += ks2; x1 += k0 + 2u;
  TF_R4(13,15,26,6)   x0 += k0;  x1 += k1 + 3u;
  TF_R4(17,29,16,24)  x0 += k1;  x1 += ks2 + 4u;
  TF_R4(13,15,26,6)   x0 += ks2; x1 += k0 + 5u;
#undef TF_R4
  o0 = x0; o1 = x1;
}

// tanh via hw exp2 + rcp + 1 Newton step: <=1 ulp (verified exact-index r3/r5)
__device__ __forceinline__ float nr_tanh(float x) {
  const float Chi = 2.8853900432586670f;
  const float Clo = 3.8519259822379735e-08f;
  float m = fmaf(x, Chi, x * Clo);
  m = fminf(m, 126.0f);
  float tt = __builtin_amdgcn_exp2f(m);
  float d  = tt + 1.0f;
  float r  = __builtin_amdgcn_rcpf(d);
  r = r * fmaf(-d, r, 2.0f);
  return fmaf(-2.0f, r, 1.0f);
}

// 32-wide f64 sub-dot of float4 arrays (shared by k_a2 and decode step-0)
__device__ __forceinline__ double dot32(const float4* __restrict__ a,
                                        const float4* __restrict__ bp) {
  double s = 0.0;
#pragma unroll
  for (int q = 0; q < 8; ++q) {
    float4 x = a[q], y = bp[q];
    s += (double)x.x * (double)y.x + (double)x.y * (double)y.y
       + (double)x.z * (double)y.z + (double)x.w * (double)y.w;
  }
  return s;
}

// ======================= precompute kernels =======================
__global__ void k1_mats(const float* __restrict__ Wv, const float* __restrict__ Wq,
                        const float* __restrict__ liw, const float* __restrict__ bvv,
                        float* __restrict__ M1T, float* __restrict__ M2T,
                        float* __restrict__ rest0) {
  int e = blockIdx.x, h = threadIdx.x;
  __shared__ float wrow[NE];
  if (e < 256) {
    wrow[h] = Wv[e * NE + h];
    __syncthreads();
    double a = 0.0;
    for (int k = 0; k < NE; ++k) a += (double)wrow[k] * (double)Wq[k * NH + h];
    if (e < 128) M1T[h * NE + e] = (float)a;
    else         M2T[h * NE + (e - 128)] = (float)a;
  } else {
    double a = 0.0;
    for (int k = 0; k < 2 * NE; ++k) a += (double)liw[k] * (double)Wv[k * NE + h];
    rest0[h] = (float)a + bvv[h];
  }
}

__global__ void k2_base(const float* __restrict__ cv, const float* __restrict__ Wc,
                        const float* __restrict__ bc, const float* __restrict__ bvv,
                        const float* __restrict__ Wq, const float* __restrict__ rest0,
                        double* __restrict__ qqbase, float* __restrict__ qq0) {
  int b = blockIdx.x, h = threadIdx.x;
  int b256 = b << 8;
  __shared__ float meanL[NE], hbarL[NE];
  double ms = 0.0;
  for (int s = 0; s < NS; ++s) ms += (double)cv[((size_t)b256 + s) * NE + h];
  meanL[h] = (float)(ms * (1.0 / 256.0));
  __syncthreads();
  double a = 0.0;
  for (int e = 0; e < NE; ++e) a += (double)meanL[e] * (double)Wc[e * NE + h];
  hbarL[h] = (float)a + bc[h];
  __syncthreads();
  double ab = 0.0, a0 = 0.0;
  for (int k = 0; k < NE; ++k) {
    double w = (double)Wq[k * NH + h];
    ab += (double)(hbarL[k] + bvv[k]) * w;
    a0 += (double)(hbarL[k] + rest0[k]) * w;
  }
  qqbase[(size_t)b * NH + h] = ab;
  qq0[(size_t)b * NH + h] = (float)a0;
}

// k_a2: A2[b][s][h] = f64 dot(cv[b][s][:], M2T[h][:]) for ALL rows, once.
// grid = NBATCH*8 blocks x 256 threads; block handles 32 s-rows of one b.
__global__ __launch_bounds__(256)
void k_a2(const float* __restrict__ cv, const float* __restrict__ M2T,
          double* __restrict__ A2) {
  const int b  = blockIdx.x >> 3;
  const int s0 = (blockIdx.x & 7) << 5;       // 32 rows
  const int t  = threadIdx.x;
  const int b256 = b << 8;
  __shared__ float cvS[32][132];               // padded
  for (int idx = t; idx < 32 * NE; idx += 256) {
    int r = idx >> 7, c = idx & 127;
    cvS[r][c] = cv[((size_t)(b256 + s0 + r)) * NE + c];
  }
  __syncthreads();
  const int sLoc = t >> 3, hg = t & 7;        // thread: one row, 16 h values
  const float4* crow = (const float4*)&cvS[sLoc][0];
  double* arow = A2 + ((size_t)(b256 + s0 + sLoc)) * NH;
#pragma unroll 4
  for (int hh = 0; hh < 16; ++hh) {
    int h = hg * 16 + hh;
    const float4* m2p = (const float4*)(M2T + (size_t)h * NE);
    double c0 = dot32(crow,      m2p);
    double c1 = dot32(crow + 8,  m2p + 8);
    double c2 = dot32(crow + 16, m2p + 16);
    double c3 = dot32(crow + 24, m2p + 24);
    arow[h] = (c0 + c1) + (c2 + c3);
  }
}

// ======================= main decode kernel =======================
struct MainSh {
  alignas(16) float  qq[NH];
  alignas(16) float  vvf[NH];
  alignas(8)  double partA[NS];
  float  logitArr[NS];
  alignas(8)  double base128[NH];
  uint2  keyL[NSTEPS];
  float  redV[8];
  float  redS[8];
  int    redI[8];
};

struct PreSh {
  float cvS[NS][33];
  float wS[32][NH];
};

template <int MODE>   // 0: stream M2T per step; 1: A2 precomputed
__global__ __launch_bounds__(512, 4)
void decode_main(const float* __restrict__ cv,
                 const float* __restrict__ mask_in,
                 const float* __restrict__ Wref,
                 const float* __restrict__ vvec,
                 const double* __restrict__ qqbase,
                 const float* __restrict__ M1T,
                 const float* __restrict__ M2T,
                 const float* __restrict__ qq0,
                 const double* __restrict__ A2,
                 float* __restrict__ out) {
  const int b = blockIdx.x;
  const int t = threadIdx.x;
  const int b256 = b << 8;
  const int i = t & 255;          // list position (r3 layout, conflict-free)
  const int halfo = t >> 8;
  const int hb = halfo << 6;

  __shared__ union { PreSh pre; MainSh m; } sh;
  __shared__ short rowIdA[NS], rowIdB[NS], posA[NS], posB[NS];
  __shared__ int nActSh[2], jSh[2], tmp8[4];
  __shared__ alignas(16) float refScratch[NE];

  // ---------- build initial active-row list ----------
  bool act0 = false;
  if (t < NS) {
    act0 = !((t == 0) || (mask_in[(size_t)b256 + t] > 0.0f));
    uint64_t mb = __ballot(act0);
    int lane = t & 63, w = t >> 6;
    int pre = __popcll(mb & (((uint64_t)1 << lane) - 1));
    if (lane == 0) tmp8[w] = (int)__popcll(mb);
    posA[t] = (short)pre;
  }
  __syncthreads();
  if (t < NS) {
    int base = 0;
    for (int k = 0; k < (t >> 6); ++k) base += tmp8[k];
    int p = base + (int)posA[t];
    if (act0) rowIdA[p] = (short)t;
    posA[t] = (short)p;
  }
  if (t == 0) {
    nActSh[0] = tmp8[0] + tmp8[1] + tmp8[2] + tmp8[3];
    jSh[0] = -1;
  }
  __syncthreads();
  const int nAct0 = nActSh[0];

  // ---------- Phase 1: refr = ref[myRow0][hb..hb+64) (bit-identical chunking) ----------
  const int myRow0 = (i < nAct0) ? (int)rowIdA[i] : 0;
  float refr[64];
#pragma unroll
  for (int j = 0; j < 64; ++j) refr[j] = 0.0f;

  for (int ec = 0; ec < 4; ++ec) {
    __syncthreads();
    for (int ii = t; ii < 32 * NH; ii += 512) {
      int r = ii >> 7, c = ii & 127;
      sh.pre.wS[r][c] = Wref[(ec * 32 + r) * NH + c];
    }
    for (int ii = t; ii < NS * 32; ii += 512) {
      int r = ii >> 5, c = ii & 31;
      sh.pre.cvS[r][c] = cv[((size_t)b256 + r) * NE + ec * 32 + c];
    }
    __syncthreads();
    for (int hc = 0; hc < 8; ++hc) {
      double a[8] = {0,0,0,0,0,0,0,0};
      for (int e = 0; e < 32; ++e) {
        double cd = (double)sh.pre.cvS[myRow0][e];
        const float* wp = &sh.pre.wS[e][hb + hc * 8];
#pragma unroll
        for (int j = 0; j < 8; ++j) a[j] += cd * (double)wp[j];
      }
#pragma unroll
      for (int j = 0; j < 8; ++j) refr[hc * 8 + j] += (float)a[j];
    }
  }
  __syncthreads();  // pre dead, m live

  // ---------- prologue ----------
  if (t < NSTEPS) {
    uint32_t o0, o1;
    tf2x32(0u, 42u, 0u, (uint32_t)t, o0, o1);
    sh.m.keyL[t] = make_uint2(o0, o1);
  }
  if (t < NH) {
    sh.m.vvf[t] = vvec[t];
    sh.m.qq[t] = qq0[(size_t)b * NH + t];
  }
  __syncthreads();

  // ---------- 255 decode steps ----------
  for (int step = 0; step < NSTEPS; ++step) {
    const int cur = step & 1;
    const short* rowId_c = cur ? rowIdB : rowIdA;
    const short* pos_c   = cur ? posB   : posA;
    short* rowId_n = cur ? rowIdA : rowIdB;
    short* pos_n   = cur ? posA   : posB;
    const int nA    = nActSh[cur];
    const int jPrev = jSh[cur];
    const bool active = (i < nA);
    const int myRow = active ? (int)rowId_c[i] : 0;

    // adoption: the pair that inherited the donor row reloads its refr slice
    if (jPrev >= 0 && i == jPrev) {
      const float4* rs4 = (const float4*)(refScratch + hb);
#pragma unroll
      for (int q = 0; q < 16; ++q) {
        float4 v4 = rs4[q];
        refr[4 * q + 0] = v4.x; refr[4 * q + 1] = v4.y;
        refr[4 * q + 2] = v4.z; refr[4 * q + 3] = v4.w;
      }
    }

    // gumbel for (step, myRow) on upper active threads
    float g = 0.0f;
    if (halfo && active) {
      uint2 key = sh.m.keyL[step];
      uint32_t o0, o1;
      tf2x32(key.x, key.y, 0u, (uint32_t)(b256 + myRow), o0, o1);
      uint32_t bits = o0 ^ o1;
      float f = __uint_as_float((bits >> 9) | 0x3f800000u) - 1.0f;
      float u = (f == 0.0f) ? 1.17549435e-38f : f;
      float l1 = -logf(u);
      g = -logf(l1);
    }

    // tanh partial over this thread's 64-wide h-slice
    double accH = 0.0;
    if (active) {
      double a0 = 0, a1 = 0, a2 = 0, a3 = 0;
      const float4* qq4 = (const float4*)(sh.m.qq + hb);
      const float4* vv4 = (const float4*)(sh.m.vvf + hb);
#pragma unroll
      for (int q = 0; q < 16; ++q) {
        float4 qv = qq4[q];
        float4 wv = vv4[q];
        a0 += (double)nr_tanh(qv.x + refr[4 * q + 0]) * (double)wv.x;
        a1 += (double)nr_tanh(qv.y + refr[4 * q + 1]) * (double)wv.y;
        a2 += (double)nr_tanh(qv.z + refr[4 * q + 2]) * (double)wv.z;
        a3 += (double)nr_tanh(qv.w + refr[4 * q + 3]) * (double)wv.w;
      }
      accH = (a0 + a1) + (a2 + a3);
      if (!halfo) sh.m.partA[i] = accH;
    }
    __syncthreads();  // B1

    if (halfo) {
      float val = SENT_NEG; int vRow = 0x7fffffff; float term = 0.0f;
      if (active) {
        float u_ = (float)(sh.m.partA[i] + accH);
        float logit = 10.0f * (float)tanh((double)u_);
        sh.m.logitArr[myRow] = logit;
        term = expf(logit);
        val = logit + g;
        vRow = myRow;
      }
      float bvv = val; int bR = vRow; float bss = term;
#pragma unroll
      for (int mm = 1; mm <= 32; mm <<= 1) {
        float ov = __shfl_xor(bvv, mm, 64);
        int   oR = __shfl_xor(bR,  mm, 64);
        float os = __shfl_xor(bss, mm, 64);
        bss += os;
        if (ov > bvv || (ov == bvv && oR < bR)) { bvv = ov; bR = oR; }
      }
      if ((t & 63) == 0) {
        int w = t >> 6;   // 4..7
        sh.m.redV[w] = bvv; sh.m.redI[w] = bR; sh.m.redS[w] = bss;
      }
    }
    __syncthreads();  // B2

    float BV = sh.m.redV[4]; int BR = sh.m.redI[4];
#pragma unroll
    for (int k = 5; k < 8; ++k) {
      float ov = sh.m.redV[k]; int oR = sh.m.redI[k];
      if (ov > BV || (ov == BV && oR < BR)) { BV = ov; BR = oR; }
    }
    if ((unsigned)BR > 255u) BR = 0;
    const int BI = BR;
    const int jj = (int)pos_c[BI];

    if (t == 0) {
      float SS = (sh.m.redS[4] + sh.m.redS[5]) + (sh.m.redS[6] + sh.m.redS[7]);
      float lp = sh.m.logitArr[BI] - (float)log((double)SS);
      out[(size_t)b * NSTEPS + step] = (float)BI;
      out[(size_t)NBATCH * NSTEPS + (size_t)b * NSTEPS + step] = lp;
      nActSh[cur ^ 1] = nA - 1;
      jSh[cur ^ 1] = (jj < nA - 1) ? jj : -1;
    }

    if (t < NS) {
      int donorRow = (int)rowId_c[nA - 1];
      short rid = (t == jj) ? (short)donorRow : rowId_c[t];
      rowId_n[t] = rid;
      if (t < nA - 1) pos_n[rid] = (short)t;
    }
    if (jj < nA - 1 && i == nA - 1) {
      float4* rs4 = (float4*)(refScratch + hb);
#pragma unroll
      for (int q = 0; q < 16; ++q)
        rs4[q] = make_float4(refr[4 * q + 0], refr[4 * q + 1],
                             refr[4 * q + 2], refr[4 * q + 3]);
    }

    // ---- qq update ----
    if (step + 1 < NSTEPS) {
      if (MODE == 1) {
        if (step == 0) {
          const int hq = t >> 2, kq = t & 3;
          const float4* hrow = (const float4*)(cv + (size_t)(b256 + BI) * NE + kq * 32);
          const float4* m1p  = (const float4*)(M1T + (size_t)hq * NE + kq * 32);
          double am = dot32(hrow, m1p);
          am += __shfl_xor(am, 1, 64);
          am += __shfl_xor(am, 2, 64);
          if (kq == 0) {
            double dbase = qqbase[(size_t)b * NH + hq] + am;
            sh.m.base128[hq] = dbase;
            sh.m.qq[hq] = (float)(dbase + A2[(size_t)(b256 + BI) * NH + hq]);
          }
        } else if (t < NH) {
          sh.m.qq[t] = (float)(sh.m.base128[t] + A2[(size_t)(b256 + BI) * NH + t]);
        }
      } else {
        const int hq = t >> 2, kq = t & 3;
        const float4* hrow = (const float4*)(cv + (size_t)(b256 + BI) * NE + kq * 32);
        const float4* m2p  = (const float4*)(M2T + (size_t)hq * NE + kq * 32);
        double a2 = dot32(hrow, m2p);
        a2 += __shfl_xor(a2, 1, 64);
        a2 += __shfl_xor(a2, 2, 64);
        if (step == 0) {
          const float4* m1p = (const float4*)(M1T + (size_t)hq * NE + kq * 32);
          double am = dot32(hrow, m1p);
          am += __shfl_xor(am, 1, 64);
          am += __shfl_xor(am, 2, 64);
          if (kq == 0) {
            double dbase = qqbase[(size_t)b * NH + hq] + am;
            sh.m.base128[hq] = dbase;
            sh.m.qq[hq] = (float)(dbase + a2);
          }
        } else if (kq == 0) {
          sh.m.qq[hq] = (float)(sh.m.base128[hq] + a2);
        }
      }
    }
    __syncthreads();  // B3
  }
}

// ======================= round-2 passing kernel (no-ws fallback, unchanged) ==========
__device__ __forceinline__ float fast_tanh_ref(float x) {
  const float Chi = 2.8853900432586670f;
  const float Clo = 3.8519259822379735e-08f;
  float m = fmaf(x, Chi, x * Clo);
  float tt = exp2f(m);
  return 1.0f - 2.0f / (tt + 1.0f);
}

struct MainShR {
  float  query[NE];
  float  qq[NH];
  float  hbar[NE];
  float  inith[NE];
  float  hcur[NE];
  alignas(16) double vvd[NH];
  float  logitArr[NS];
  float  maskArr[NS];
  uint2  keyL[NSTEPS];
  float  meanv[NE];
  float  redV[4];
  int    redI[4];
  double redS[4];
  int    idxSh;
};
struct PreShR {
  float cvS[NS][33];
  float wS[32][NH];
};

__global__ __launch_bounds__(256, 2)
void decoder_kernel_ref(const float* __restrict__ cv, const float* __restrict__ mask_in,
                        const float* __restrict__ liw, const float* __restrict__ Wc,
                        const float* __restrict__ bc, const float* __restrict__ Wv,
                        const float* __restrict__ bv, const float* __restrict__ Wq,
                        const float* __restrict__ Wref, const float* __restrict__ vvec,
                        float* __restrict__ out) {
  const int b = blockIdx.x;
  const int t = threadIdx.x;
  const int b256 = b << 8;
  __shared__ union { PreShR pre; MainShR m; } sh;

  float refr[NH];
#pragma unroll
  for (int h = 0; h < NH; ++h) refr[h] = 0.0f;
  for (int ec = 0; ec < 4; ++ec) {
    const int e0 = ec * 32;
    __syncthreads();
    for (int i = t; i < 32 * NH; i += 256) {
      int r = i >> 7, h = i & 127;
      sh.pre.wS[r][h] = Wref[(e0 + r) * NH + h];
    }
    for (int i = t; i < NS * 32; i += 256) {
      int s2 = i >> 5, j = i & 31;
      sh.pre.cvS[s2][j] = cv[((size_t)b256 + s2) * NE + e0 + j];
    }
    __syncthreads();
#pragma unroll
    for (int hc = 0; hc < 16; ++hc) {
      double a[8] = {0,0,0,0,0,0,0,0};
      for (int e = 0; e < 32; ++e) {
        double cd = (double)sh.pre.cvS[t][e];
#pragma unroll
        for (int j = 0; j < 8; ++j) a[j] += cd * (double)sh.pre.wS[e][hc * 8 + j];
      }
#pragma unroll
      for (int j = 0; j < 8; ++j) refr[hc * 8 + j] += (float)a[j];
    }
  }
  __syncthreads();

  if (t < NSTEPS) {
    uint32_t o0, o1;
    tf2x32(0u, 42u, 0u, (uint32_t)t, o0, o1);
    sh.m.keyL[t] = make_uint2(o0, o1);
  }
  if (t < NH) sh.m.vvd[t] = (double)vvec[t];
  sh.m.maskArr[t] = (mask_in[(size_t)b256 + t] > 0.0f || t == 0) ? 1.0f : 0.0f;
  if (t < NE) {
    double s64 = 0.0;
    for (int s2 = 0; s2 < NS; ++s2) s64 += (double)cv[((size_t)b256 + s2) * NE + t];
    sh.m.meanv[t] = (float)(s64 * (1.0 / 256.0));
  }
  __syncthreads();
  if (t < NE) {
    double acc = 0.0;
    for (int e = 0; e < NE; ++e) acc += (double)sh.m.meanv[e] * (double)Wc[e * NE + t];
    float hbv = (float)acc + bc[t];
    sh.m.hbar[t] = hbv;
    double acc2 = 0.0;
    for (int k = 0; k < 2 * NE; ++k) acc2 += (double)liw[k] * (double)Wv[k * NE + t];
    float r0 = (float)acc2 + bv[t];
    sh.m.query[t] = hbv + r0;
  }
  __syncthreads();

  for (int step = 0; step < NSTEPS; ++step) {
    if (t < NH) {
      double acc = 0.0;
      for (int k = 0; k < NE; ++k) acc += (double)sh.m.query[k] * (double)Wq[k * NH + t];
      sh.m.qq[t] = (float)acc;
    }
    __syncthreads();

    float logit;
    bool masked = (sh.m.maskArr[t] != 0.0f);
    if (!masked) {
      double a0 = 0.0, a1 = 0.0, a2 = 0.0, a3 = 0.0;
      const float4*  qq4 = (const float4*)sh.m.qq;
      const double2* vv2 = (const double2*)sh.m.vvd;
#pragma unroll
      for (int h4 = 0; h4 < 32; ++h4) {
        float4  q  = qq4[h4];
        double2 va = vv2[2 * h4];
        double2 vb = vv2[2 * h4 + 1];
        a0 += (double)fast_tanh_ref(q.x + refr[4 * h4 + 0]) * va.x;
        a1 += (double)fast_tanh_ref(q.y + refr[4 * h4 + 1]) * va.y;
        a2 += (double)fast_tanh_ref(q.z + refr[4 * h4 + 2]) * vb.x;
        a3 += (double)fast_tanh_ref(q.w + refr[4 * h4 + 3]) * vb.y;
      }
      float u_ = (float)((a0 + a1) + (a2 + a3));
      logit = 10.0f * (float)tanh((double)u_);
    } else {
      logit = NEGINF;
    }
    sh.m.logitArr[t] = logit;

    uint2 key = sh.m.keyL[step];
    uint32_t j = (uint32_t)(b256 + t);
    uint32_t o0, o1;
    tf2x32(key.x, key.y, 0u, j, o0, o1);
    uint32_t bits = o0 ^ o1;
    float f = __uint_as_float((bits >> 9) | 0x3f800000u) - 1.0f;
    float u = (f == 0.0f) ? 1.17549435e-38f : f;
    float l1 = (float)(-log((double)u));
    float g  = (float)(-log((double)l1));
    float val = logit + g;
    double term = exp((double)logit);

    float bv_ = val; int bi = t; double bs = term;
#pragma unroll
    for (int m = 1; m <= 32; m <<= 1) {
      float  ov = __shfl_xor(bv_, m, 64);
      int    oi = __shfl_xor(bi,  m, 64);
      double os = __shfl_xor(bs,  m, 64);
      if (ov > bv_ || (ov == bv_ && oi < bi)) { bv_ = ov; bi = oi; }
      bs += os;
    }
    int w = t >> 6;
    if ((t & 63) == 0) { sh.m.redV[w] = bv_; sh.m.redI[w] = bi; sh.m.redS[w] = bs; }
    __syncthreads();

    if (t == 0) {
      float BV = sh.m.redV[0]; int BI = sh.m.redI[0];
      for (int k = 1; k < 4; ++k) {
        float ov = sh.m.redV[k]; int oi = sh.m.redI[k];
        if (ov > BV || (ov == BV && oi < BI)) { BV = ov; BI = oi; }
      }
      double SS = ((sh.m.redS[0] + sh.m.redS[1]) + (sh.m.redS[2] + sh.m.redS[3]));
      sh.m.idxSh = BI;
      float lp = sh.m.logitArr[BI] - (float)log(SS);
      out[(size_t)b * NSTEPS + step] = (float)BI;
      out[(size_t)NBATCH * NSTEPS + (size_t)b * NSTEPS + step] = lp;
    }
    __syncthreads();

    int idx = sh.m.idxSh;
    if (t == idx) sh.m.maskArr[t] = 1.0f;
    if (t < NE) {
      float hc = cv[((size_t)b256 + idx) * NE + t];
      sh.m.hcur[t] = hc;
      if (step == 0) sh.m.inith[t] = hc;
    }
    __syncthreads();

    if (t < NE) {
      double acc2 = 0.0;
      for (int k = 0; k < NE; ++k) acc2 += (double)sh.m.inith[k] * (double)Wv[k * NE + t];
      for (int k = 0; k < NE; ++k) acc2 += (double)sh.m.hcur[k] * (double)Wv[(NE + k) * NE + t];
      float mm = (float)acc2 + bv[t];
      sh.m.query[t] = sh.m.hbar[t] + mm;
    }
    __syncthreads();
  }
}

extern "C" void kernel_launch(void* const* d_in, const int* in_sizes, int n_in,
                              void* d_out, int out_size, void* d_ws, size_t ws_size,
                              hipStream_t stream) {
  const float* cv   = (const float*)d_in[0];
  const float* mask = (const float*)d_in[2];
  const float* liw  = (const float*)d_in[3];
  const float* Wc   = (const float*)d_in[4];
  const float* bc   = (const float*)d_in[5];
  const float* Wv   = (const float*)d_in[6];
  const float* bv   = (const float*)d_in[7];
  const float* Wq   = (const float*)d_in[8];
  const float* Wref = (const float*)d_in[9];
  const float* vv   = (const float*)d_in[10];
  (void)in_sizes; (void)n_in; (void)out_size;

  const size_t SZ_QQB = (size_t)NBATCH * NH * sizeof(double);     // 512 KB
  const size_t SZ_M   = (size_t)NE * NH * sizeof(float);          // 64 KB each
  const size_t SZ_QQ0 = (size_t)NBATCH * NH * sizeof(float);      // 256 KB
  const size_t SZ_A2  = (size_t)NBATCH * NS * NH * sizeof(double);// 134 MB
  const size_t need_min = SZ_QQB + 2 * SZ_M + SZ_QQ0 + 512;
  const size_t need_pre = need_min + SZ_A2;

  if (ws_size >= need_min) {
    char* p = (char*)d_ws;
    double* qqbase = (double*)p;            p += SZ_QQB;
    float*  M1T    = (float*)p;             p += SZ_M;
    float*  M2T    = (float*)p;             p += SZ_M;
    float*  qq0    = (float*)p;             p += SZ_QQ0;
    float*  rest0  = (float*)p;             p += 512;
    double* A2     = (double*)p;

    k1_mats<<<257, 128, 0, stream>>>(Wv, Wq, liw, bv, M1T, M2T, rest0);
    k2_base<<<NBATCH, 128, 0, stream>>>(cv, Wc, bc, bv, Wq, rest0, qqbase, qq0);
    if (ws_size >= need_pre) {
      k_a2<<<NBATCH * 8, 256, 0, stream>>>(cv, M2T, A2);
      decode_main<1><<<NBATCH, 512, 0, stream>>>(cv, mask, Wref, vv, qqbase, M1T,
                                                 M2T, qq0, A2, (float*)d_out);
    } else {
      decode_main<0><<<NBATCH, 512, 0, stream>>>(cv, mask, Wref, vv, qqbase, M1T,
                                                 M2T, qq0, nullptr, (float*)d_out);
    }
  } else {
    decoder_kernel_ref<<<NBATCH, 256, 0, stream>>>(cv, mask, liw, Wc, bc, Wv, bv,
                                                   Wq, Wref, vv, (float*)d_out);
  }
}

// Round 7
// 3587.872 us; speedup vs baseline: 1.9972x; 1.3179x over previous
//
#include <hip/hip_runtime.h>
#include <hip/hip_bf16.h>
#include <stdint.h>
#include <math.h>

#define NBATCH 512
#define NS 256
#define NE 128
#define NH 128
#define NSTEPS 255
#define NEGINF -1e8f
#define SENT_NEG -1e30f

// ---------------- threefry2x32 (partitionable path, verified r2..r6) ----------------
__device__ __forceinline__ uint32_t rotl32(uint32_t x, uint32_t r) {
  return (x << r) | (x >> (32u - r));
}

__device__ __forceinline__ void tf2x32(uint32_t k0, uint32_t k1,
                                       uint32_t x0, uint32_t x1,
                                       uint32_t& o0, uint32_t& o1) {
  uint32_t ks2 = k0 ^ k1 ^ 0x1BD11BDAu;
  x0 += k0; x1 += k1;
#define TF_R4(a,b,c,d) \
  x0 += x1; x1 = rotl32(x1,a); x1 ^= x0; \
  x0 += x1; x1 = rotl32(x1,b); x1 ^= x0; \
  x0 += x1; x1 = rotl32(x1,c); x1 ^= x0; \
  x0 += x1; x1 = rotl32(x1,d); x1 ^= x0;
  TF_R4(13,15,26,6)   x0 += k1;  x1 += ks2 + 1u;
  TF_R4(17,29,16,24)  x0 += ks2; x1 += k0 + 2u;
  TF_R4(13,15,26,6)   x0 += k0;  x1 += k1 + 3u;
  TF_R4(17,29,16,24)  x0 += k1;  x1 += ks2 + 4u;
  TF_R4(13,15,26,6)   x0 += ks2; x1 += k0 + 5u;
#undef TF_R4
  o0 = x0; o1 = x1;
}

__device__ __forceinline__ float gumbel_of(uint2 key, uint32_t j) {
  uint32_t o0, o1;
  tf2x32(key.x, key.y, 0u, j, o0, o1);
  uint32_t bits = o0 ^ o1;
  float f = __uint_as_float((bits >> 9) | 0x3f800000u) - 1.0f;
  float u = (f == 0.0f) ? 1.17549435e-38f : f;
  float l1 = -logf(u);
  return -logf(l1);
}

// tanh via hw exp2 + rcp + 1 Newton step (verified exact-index r3..r6)
__device__ __forceinline__ float nr_tanh(float x) {
  const float Chi = 2.8853900432586670f;
  const float Clo = 3.8519259822379735e-08f;
  float m = fmaf(x, Chi, x * Clo);
  m = fminf(m, 126.0f);
  float tt = __builtin_amdgcn_exp2f(m);
  float d  = tt + 1.0f;
  float r  = __builtin_amdgcn_rcpf(d);
  r = r * fmaf(-d, r, 2.0f);
  return fmaf(-2.0f, r, 1.0f);
}

// 32-wide f64 sub-dot of float4 arrays (MODE0 / step-0 paths)
__device__ __forceinline__ double dot32(const float4* __restrict__ a,
                                        const float4* __restrict__ bp) {
  double s = 0.0;
#pragma unroll
  for (int q = 0; q < 8; ++q) {
    float4 x = a[q], y = bp[q];
    s += (double)x.x * (double)y.x + (double)x.y * (double)y.y
       + (double)x.z * (double)y.z + (double)x.w * (double)y.w;
  }
  return s;
}

__device__ __forceinline__ double dot4d(float4 a, float4 b) {
  return ((double)a.x * (double)b.x + (double)a.y * (double)b.y)
       + ((double)a.z * (double)b.z + (double)a.w * (double)b.w);
}

// ======================= precompute kernels =======================
__global__ void k1_mats(const float* __restrict__ Wv, const float* __restrict__ Wq,
                        const float* __restrict__ liw, const float* __restrict__ bvv,
                        float* __restrict__ M1T, float* __restrict__ M2T,
                        float* __restrict__ rest0) {
  int e = blockIdx.x, h = threadIdx.x;
  __shared__ float wrow[NE];
  if (e < 256) {
    wrow[h] = Wv[e * NE + h];
    __syncthreads();
    double a = 0.0;
    for (int k = 0; k < NE; ++k) a += (double)wrow[k] * (double)Wq[k * NH + h];
    if (e < 128) M1T[h * NE + e] = (float)a;
    else         M2T[h * NE + (e - 128)] = (float)a;
  } else {
    double a = 0.0;
    for (int k = 0; k < 2 * NE; ++k) a += (double)liw[k] * (double)Wv[k * NE + h];
    rest0[h] = (float)a + bvv[h];
  }
}

__global__ void k2_base(const float* __restrict__ cv, const float* __restrict__ Wc,
                        const float* __restrict__ bc, const float* __restrict__ bvv,
                        const float* __restrict__ Wq, const float* __restrict__ rest0,
                        double* __restrict__ qqbase, float* __restrict__ qq0) {
  int b = blockIdx.x, h = threadIdx.x;
  int b256 = b << 8;
  __shared__ float meanL[NE], hbarL[NE];
  double ms = 0.0;
  for (int s = 0; s < NS; ++s) ms += (double)cv[((size_t)b256 + s) * NE + h];
  meanL[h] = (float)(ms * (1.0 / 256.0));
  __syncthreads();
  double a = 0.0;
  for (int e = 0; e < NE; ++e) a += (double)meanL[e] * (double)Wc[e * NE + h];
  hbarL[h] = (float)a + bc[h];
  __syncthreads();
  double ab = 0.0, a0 = 0.0;
  for (int k = 0; k < NE; ++k) {
    double w = (double)Wq[k * NH + h];
    ab += (double)(hbarL[k] + bvv[k]) * w;
    a0 += (double)(hbarL[k] + rest0[k]) * w;
  }
  qqbase[(size_t)b * NH + h] = ab;
  qq0[(size_t)b * NH + h] = (float)a0;
}

// k_a2v2: A2[b][s][h] = f64 dot(cv[b][s][:], M2T[h][:]).
// Thread owns ONE h column (M2T row in registers, loaded once); cv rows
// broadcast from LDS; writes 128 consecutive doubles per wave (coalesced).
__global__ __launch_bounds__(256)
void k_a2v2(const float* __restrict__ cv, const float* __restrict__ M2T,
            double* __restrict__ A2) {
  const int b  = blockIdx.x >> 3;
  const int s0 = (blockIdx.x & 7) << 5;      // 32 rows per block
  const int t  = threadIdx.x;
  const int sl = t >> 7;                      // 0..1
  const int h  = t & 127;
  const int b256 = b << 8;
  __shared__ float cvS[32][129];
  for (int idx = t; idx < 32 * NE; idx += 256) {
    int r = idx >> 7, c = idx & 127;
    cvS[r][c] = cv[((size_t)(b256 + s0 + r)) * NE + c];
  }
  __syncthreads();
  float4 m2r[32];
  {
    const float4* m2p = (const float4*)(M2T + (size_t)h * NE);
#pragma unroll
    for (int q = 0; q < 32; ++q) m2r[q] = m2p[q];
  }
#pragma unroll 1
  for (int it = 0; it < 16; ++it) {
    const int sLoc = (it << 1) + sl;
    const float4* cr4 = (const float4*)&cvS[sLoc][0];
    double c0 = 0, c1 = 0, c2 = 0, c3 = 0;
#pragma unroll
    for (int q = 0; q < 8; ++q) {
      c0 += dot4d(cr4[q * 4 + 0], m2r[q * 4 + 0]);
      c1 += dot4d(cr4[q * 4 + 1], m2r[q * 4 + 1]);
      c2 += dot4d(cr4[q * 4 + 2], m2r[q * 4 + 2]);
      c3 += dot4d(cr4[q * 4 + 3], m2r[q * 4 + 3]);
    }
    A2[((size_t)(b256 + s0 + sLoc)) * NH + h] = (c0 + c1) + (c2 + c3);
  }
}

// ======================= main decode kernel =======================
struct MainSh {
  alignas(16) float  qq[NH];
  alignas(16) float  vvf[NH];
  alignas(8)  double partA[NS];
  float  logitArr[NS];
  alignas(8)  double base128[NH];
  uint2  keyL[NSTEPS];
  float  redV[8];
  float  redS[8];
  int    redI[8];
};

struct PreSh {
  float cvS[NS][33];
  float wS[32][NH];
};

template <int MODE>   // 0: stream M2T per step; 1: A2 precomputed
__global__ __launch_bounds__(512, 4)
void decode_main(const float* __restrict__ cv,
                 const float* __restrict__ mask_in,
                 const float* __restrict__ Wref,
                 const float* __restrict__ vvec,
                 const double* __restrict__ qqbase,
                 const float* __restrict__ M1T,
                 const float* __restrict__ M2T,
                 const float* __restrict__ qq0,
                 const double* __restrict__ A2,
                 float* __restrict__ out) {
  const int b = blockIdx.x;
  const int t = threadIdx.x;
  const int b256 = b << 8;
  const int i = t & 255;
  const int halfo = t >> 8;
  const int hb = halfo << 6;

  __shared__ union { PreSh pre; MainSh m; } sh;
  __shared__ short rowIdA[NS], rowIdB[NS], posA[NS], posB[NS];
  __shared__ int nActSh[2], jSh[2], tmp8[4];
  __shared__ alignas(16) float refScratch[NE];

  // ---------- build initial active-row list ----------
  bool act0 = false;
  if (t < NS) {
    act0 = !((t == 0) || (mask_in[(size_t)b256 + t] > 0.0f));
    uint64_t mb = __ballot(act0);
    int lane = t & 63, w = t >> 6;
    int pre = __popcll(mb & (((uint64_t)1 << lane) - 1));
    if (lane == 0) tmp8[w] = (int)__popcll(mb);
    posA[t] = (short)pre;
  }
  __syncthreads();
  if (t < NS) {
    int base = 0;
    for (int k = 0; k < (t >> 6); ++k) base += tmp8[k];
    int p = base + (int)posA[t];
    if (act0) rowIdA[p] = (short)t;
    posA[t] = (short)p;
  }
  if (t == 0) {
    nActSh[0] = tmp8[0] + tmp8[1] + tmp8[2] + tmp8[3];
    jSh[0] = -1;
  }
  __syncthreads();
  const int nAct0 = nActSh[0];

  // ---------- Phase 1: refr = ref[myRow0][hb..hb+64) (bit-identical chunking) ----------
  const int myRow0 = (i < nAct0) ? (int)rowIdA[i] : 0;
  float refr[64];
#pragma unroll
  for (int j = 0; j < 64; ++j) refr[j] = 0.0f;

  for (int ec = 0; ec < 4; ++ec) {
    __syncthreads();
    for (int ii = t; ii < 32 * NH; ii += 512) {
      int r = ii >> 7, c = ii & 127;
      sh.pre.wS[r][c] = Wref[(ec * 32 + r) * NH + c];
    }
    for (int ii = t; ii < NS * 32; ii += 512) {
      int r = ii >> 5, c = ii & 31;
      sh.pre.cvS[r][c] = cv[((size_t)b256 + r) * NE + ec * 32 + c];
    }
    __syncthreads();
    for (int hc = 0; hc < 8; ++hc) {
      double a[8] = {0,0,0,0,0,0,0,0};
      for (int e = 0; e < 32; ++e) {
        double cd = (double)sh.pre.cvS[myRow0][e];
        const float* wp = &sh.pre.wS[e][hb + hc * 8];
#pragma unroll
        for (int j = 0; j < 8; ++j) a[j] += cd * (double)wp[j];
      }
#pragma unroll
      for (int j = 0; j < 8; ++j) refr[hc * 8 + j] += (float)a[j];
    }
  }
  __syncthreads();  // pre dead, m live

  // ---------- prologue ----------
  if (t < NSTEPS) {
    uint32_t o0, o1;
    tf2x32(0u, 42u, 0u, (uint32_t)t, o0, o1);
    sh.m.keyL[t] = make_uint2(o0, o1);
  }
  if (t < NH) {
    sh.m.vvf[t] = vvec[t];
    sh.m.qq[t] = qq0[(size_t)b * NH + t];
  }
  __syncthreads();

  // step-0 gumbel, pipelined in register g
  float g = 0.0f;
  if (halfo && i < nAct0)
    g = gumbel_of(sh.m.keyL[0], (uint32_t)(b256 + myRow0));

  // ---------- 255 decode steps ----------
  for (int step = 0; step < NSTEPS; ++step) {
    const int cur = step & 1;
    const short* rowId_c = cur ? rowIdB : rowIdA;
    const short* pos_c   = cur ? posB   : posA;
    short* rowId_n = cur ? rowIdA : rowIdB;
    short* pos_n   = cur ? posA   : posB;
    const int nA    = nActSh[cur];
    const int jPrev = jSh[cur];
    const bool active = (i < nA);
    const int myRow = active ? (int)rowId_c[i] : 0;

    // adoption: pair that inherited the donor row reloads its refr slice
    if (jPrev >= 0 && i == jPrev) {
      const float4* rs4 = (const float4*)(refScratch + hb);
#pragma unroll
      for (int q = 0; q < 16; ++q) {
        float4 v4 = rs4[q];
        refr[4 * q + 0] = v4.x; refr[4 * q + 1] = v4.y;
        refr[4 * q + 2] = v4.z; refr[4 * q + 3] = v4.w;
      }
    }

    // tanh partial over this thread's 64-wide h-slice
    double accH = 0.0;
    if (active) {
      double a0 = 0, a1 = 0, a2 = 0, a3 = 0;
      const float4* qq4 = (const float4*)(sh.m.qq + hb);
      const float4* vv4 = (const float4*)(sh.m.vvf + hb);
#pragma unroll
      for (int q = 0; q < 16; ++q) {
        float4 qv = qq4[q];
        float4 wv = vv4[q];
        a0 += (double)nr_tanh(qv.x + refr[4 * q + 0]) * (double)wv.x;
        a1 += (double)nr_tanh(qv.y + refr[4 * q + 1]) * (double)wv.y;
        a2 += (double)nr_tanh(qv.z + refr[4 * q + 2]) * (double)wv.z;
        a3 += (double)nr_tanh(qv.w + refr[4 * q + 3]) * (double)wv.w;
      }
      accH = (a0 + a1) + (a2 + a3);
      if (!halfo) sh.m.partA[i] = accH;
    }
    __syncthreads();  // B1

    if (halfo) {
      float val = SENT_NEG; int vRow = 0x7fffffff; float term = 0.0f;
      if (active) {
        float u_ = (float)(sh.m.partA[i] + accH);
        float logit = 10.0f * (float)tanh((double)u_);
        sh.m.logitArr[myRow] = logit;
        term = expf(logit);
        val = logit + g;
        vRow = myRow;
      }
      float bvv = val; int bR = vRow; float bss = term;
#pragma unroll
      for (int mm = 1; mm <= 32; mm <<= 1) {
        float ov = __shfl_xor(bvv, mm, 64);
        int   oR = __shfl_xor(bR,  mm, 64);
        float os = __shfl_xor(bss, mm, 64);
        bss += os;
        if (ov > bvv || (ov == bvv && oR < bR)) { bvv = ov; bR = oR; }
      }
      if ((t & 63) == 0) {
        int w = t >> 6;   // 4..7
        sh.m.redV[w] = bvv; sh.m.redI[w] = bR; sh.m.redS[w] = bss;
      }
    }
    __syncthreads();  // B2

    float BV = sh.m.redV[4]; int BR = sh.m.redI[4];
#pragma unroll
    for (int k = 5; k < 8; ++k) {
      float ov = sh.m.redV[k]; int oR = sh.m.redI[k];
      if (ov > BV || (ov == BV && oR < BR)) { BV = ov; BR = oR; }
    }
    if ((unsigned)BR > 255u) BR = 0;
    const int BI = BR;
    const int jj = (int)pos_c[BI];

    // early-issue A2 row load (MODE 1, steps >= 1): latency overlaps the
    // compaction copy / out-writes / next-step gumbel below.
    double a2v = 0.0;
    if (MODE == 1 && step > 0 && step + 1 < NSTEPS && t < NH)
      a2v = A2[(size_t)(b256 + BI) * NH + t];

    if (t == 0) {
      float SS = (sh.m.redS[4] + sh.m.redS[5]) + (sh.m.redS[6] + sh.m.redS[7]);
      float lp = sh.m.logitArr[BI] - (float)log((double)SS);
      out[(size_t)b * NSTEPS + step] = (float)BI;
      out[(size_t)NBATCH * NSTEPS + (size_t)b * NSTEPS + step] = lp;
      nActSh[cur ^ 1] = nA - 1;
      jSh[cur ^ 1] = (jj < nA - 1) ? jj : -1;
    }

    if (t < NS) {
      int donorRow = (int)rowId_c[nA - 1];
      short rid = (t == jj) ? (short)donorRow : rowId_c[t];
      rowId_n[t] = rid;
      if (t < nA - 1) pos_n[rid] = (short)t;
    }
    if (jj < nA - 1 && i == nA - 1) {
      float4* rs4 = (float4*)(refScratch + hb);
#pragma unroll
      for (int q = 0; q < 16; ++q)
        rs4[q] = make_float4(refr[4 * q + 0], refr[4 * q + 1],
                             refr[4 * q + 2], refr[4 * q + 3]);
    }

    // next-step gumbel (upper threads; overlaps qq update / A2 latency)
    if (halfo && step + 1 < NSTEPS) {
      int nA_next = nA - 1;
      if (i < nA_next) {
        int ridN = (i == jj) ? (int)rowId_c[nA - 1] : myRow;
        g = gumbel_of(sh.m.keyL[step + 1], (uint32_t)(b256 + ridN));
      }
    }

    // ---- qq update ----
    if (step + 1 < NSTEPS) {
      if (MODE == 1) {
        if (step == 0) {
          const int hq = t >> 2, kq = t & 3;
          const float4* hrow = (const float4*)(cv + (size_t)(b256 + BI) * NE + kq * 32);
          const float4* m1p  = (const float4*)(M1T + (size_t)hq * NE + kq * 32);
          double am = dot32(hrow, m1p);
          am += __shfl_xor(am, 1, 64);
          am += __shfl_xor(am, 2, 64);
          if (kq == 0) {
            double dbase = qqbase[(size_t)b * NH + hq] + am;
            sh.m.base128[hq] = dbase;
            sh.m.qq[hq] = (float)(dbase + A2[(size_t)(b256 + BI) * NH + hq]);
          }
        } else if (t < NH) {
          sh.m.qq[t] = (float)(sh.m.base128[t] + a2v);
        }
      } else {
        const int hq = t >> 2, kq = t & 3;
        const float4* hrow = (const float4*)(cv + (size_t)(b256 + BI) * NE + kq * 32);
        const float4* m2p  = (const float4*)(M2T + (size_t)hq * NE + kq * 32);
        double a2 = dot32(hrow, m2p);
        a2 += __shfl_xor(a2, 1, 64);
        a2 += __shfl_xor(a2, 2, 64);
        if (step == 0) {
          const float4* m1p = (const float4*)(M1T + (size_t)hq * NE + kq * 32);
          double am = dot32(hrow, m1p);
          am += __shfl_xor(am, 1, 64);
          am += __shfl_xor(am, 2, 64);
          if (kq == 0) {
            double dbase = qqbase[(size_t)b * NH + hq] + am;
            sh.m.base128[hq] = dbase;
            sh.m.qq[hq] = (float)(dbase + a2);
          }
        } else if (kq == 0) {
          sh.m.qq[hq] = (float)(sh.m.base128[hq] + a2);
        }
      }
    }
    __syncthreads();  // B3
  }
}

// ======================= round-2 passing kernel (no-ws fallback, unchanged) ==========
__device__ __forceinline__ float fast_tanh_ref(float x) {
  const float Chi = 2.8853900432586670f;
  const float Clo = 3.8519259822379735e-08f;
  float m = fmaf(x, Chi, x * Clo);
  float tt = exp2f(m);
  return 1.0f - 2.0f / (tt + 1.0f);
}

struct MainShR {
  float  query[NE];
  float  qq[NH];
  float  hbar[NE];
  float  inith[NE];
  float  hcur[NE];
  alignas(16) double vvd[NH];
  float  logitArr[NS];
  float  maskArr[NS];
  uint2  keyL[NSTEPS];
  float  meanv[NE];
  float  redV[4];
  int    redI[4];
  double redS[4];
  int    idxSh;
};
struct PreShR {
  float cvS[NS][33];
  float wS[32][NH];
};

__global__ __launch_bounds__(256, 2)
void decoder_kernel_ref(const float* __restrict__ cv, const float* __restrict__ mask_in,
                        const float* __restrict__ liw, const float* __restrict__ Wc,
                        const float* __restrict__ bc, const float* __restrict__ Wv,
                        const float* __restrict__ bv, const float* __restrict__ Wq,
                        const float* __restrict__ Wref, const float* __restrict__ vvec,
                        float* __restrict__ out) {
  const int b = blockIdx.x;
  const int t = threadIdx.x;
  const int b256 = b << 8;
  __shared__ union { PreShR pre; MainShR m; } sh;

  float refr[NH];
#pragma unroll
  for (int h = 0; h < NH; ++h) refr[h] = 0.0f;
  for (int ec = 0; ec < 4; ++ec) {
    const int e0 = ec * 32;
    __syncthreads();
    for (int i = t; i < 32 * NH; i += 256) {
      int r = i >> 7, h = i & 127;
      sh.pre.wS[r][h] = Wref[(e0 + r) * NH + h];
    }
    for (int i = t; i < NS * 32; i += 256) {
      int s2 = i >> 5, j = i & 31;
      sh.pre.cvS[s2][j] = cv[((size_t)b256 + s2) * NE + e0 + j];
    }
    __syncthreads();
#pragma unroll
    for (int hc = 0; hc < 16; ++hc) {
      double a[8] = {0,0,0,0,0,0,0,0};
      for (int e = 0; e < 32; ++e) {
        double cd = (double)sh.pre.cvS[t][e];
#pragma unroll
        for (int j = 0; j < 8; ++j) a[j] += cd * (double)sh.pre.wS[e][hc * 8 + j];
      }
#pragma unroll
      for (int j = 0; j < 8; ++j) refr[hc * 8 + j] += (float)a[j];
    }
  }
  __syncthreads();

  if (t < NSTEPS) {
    uint32_t o0, o1;
    tf2x32(0u, 42u, 0u, (uint32_t)t, o0, o1);
    sh.m.keyL[t] = make_uint2(o0, o1);
  }
  if (t < NH) sh.m.vvd[t] = (double)vvec[t];
  sh.m.maskArr[t] = (mask_in[(size_t)b256 + t] > 0.0f || t == 0) ? 1.0f : 0.0f;
  if (t < NE) {
    double s64 = 0.0;
    for (int s2 = 0; s2 < NS; ++s2) s64 += (double)cv[((size_t)b256 + s2) * NE + t];
    sh.m.meanv[t] = (float)(s64 * (1.0 / 256.0));
  }
  __syncthreads();
  if (t < NE) {
    double acc = 0.0;
    for (int e = 0; e < NE; ++e) acc += (double)sh.m.meanv[e] * (double)Wc[e * NE + t];
    float hbv = (float)acc + bc[t];
    sh.m.hbar[t] = hbv;
    double acc2 = 0.0;
    for (int k = 0; k < 2 * NE; ++k) acc2 += (double)liw[k] * (double)Wv[k * NE + t];
    float r0 = (float)acc2 + bv[t];
    sh.m.query[t] = hbv + r0;
  }
  __syncthreads();

  for (int step = 0; step < NSTEPS; ++step) {
    if (t < NH) {
      double acc = 0.0;
      for (int k = 0; k < NE; ++k) acc += (double)sh.m.query[k] * (double)Wq[k * NH + t];
      sh.m.qq[t] = (float)acc;
    }
    __syncthreads();

    float logit;
    bool masked = (sh.m.maskArr[t] != 0.0f);
    if (!masked) {
      double a0 = 0.0, a1 = 0.0, a2 = 0.0, a3 = 0.0;
      const float4*  qq4 = (const float4*)sh.m.qq;
      const double2* vv2 = (const double2*)sh.m.vvd;
#pragma unroll
      for (int h4 = 0; h4 < 32; ++h4) {
        float4  q  = qq4[h4];
        double2 va = vv2[2 * h4];
        double2 vb = vv2[2 * h4 + 1];
        a0 += (double)fast_tanh_ref(q.x + refr[4 * h4 + 0]) * va.x;
        a1 += (double)fast_tanh_ref(q.y + refr[4 * h4 + 1]) * va.y;
        a2 += (double)fast_tanh_ref(q.z + refr[4 * h4 + 2]) * vb.x;
        a3 += (double)fast_tanh_ref(q.w + refr[4 * h4 + 3]) * vb.y;
      }
      float u_ = (float)((a0 + a1) + (a2 + a3));
      logit = 10.0f * (float)tanh((double)u_);
    } else {
      logit = NEGINF;
    }
    sh.m.logitArr[t] = logit;

    uint2 key = sh.m.keyL[step];
    uint32_t j = (uint32_t)(b256 + t);
    uint32_t o0, o1;
    tf2x32(key.x, key.y, 0u, j, o0, o1);
    uint32_t bits = o0 ^ o1;
    float f = __uint_as_float((bits >> 9) | 0x3f800000u) - 1.0f;
    float u = (f == 0.0f) ? 1.17549435e-38f : f;
    float l1 = (float)(-log((double)u));
    float g  = (float)(-log((double)l1));
    float val = logit + g;
    double term = exp((double)logit);

    float bv_ = val; int bi = t; double bs = term;
#pragma unroll
    for (int m = 1; m <= 32; m <<= 1) {
      float  ov = __shfl_xor(bv_, m, 64);
      int    oi = __shfl_xor(bi,  m, 64);
      double os = __shfl_xor(bs,  m, 64);
      if (ov > bv_ || (ov == bv_ && oi < bi)) { bv_ = ov; bi = oi; }
      bs += os;
    }
    int w = t >> 6;
    if ((t & 63) == 0) { sh.m.redV[w] = bv_; sh.m.redI[w] = bi; sh.m.redS[w] = bs; }
    __syncthreads();

    if (t == 0) {
      float BV = sh.m.redV[0]; int BI = sh.m.redI[0];
      for (int k = 1; k < 4; ++k) {
        float ov = sh.m.redV[k]; int oi = sh.m.redI[k];
        if (ov > BV || (ov == BV && oi < BI)) { BV = ov; BI = oi; }
      }
      double SS = ((sh.m.redS[0] + sh.m.redS[1]) + (sh.m.redS[2] + sh.m.redS[3]));
      sh.m.idxSh = BI;
      float lp = sh.m.logitArr[BI] - (float)log(SS);
      out[(size_t)b * NSTEPS + step] = (float)BI;
      out[(size_t)NBATCH * NSTEPS + (size_t)b * NSTEPS + step] = lp;
    }
    __syncthreads();

    int idx = sh.m.idxSh;
    if (t == idx) sh.m.maskArr[t] = 1.0f;
    if (t < NE) {
      float hc = cv[((size_t)b256 + idx) * NE + t];
      sh.m.hcur[t] = hc;
      if (step == 0) sh.m.inith[t] = hc;
    }
    __syncthreads();

    if (t < NE) {
      double acc2 = 0.0;
      for (int k = 0; k < NE; ++k) acc2 += (double)sh.m.inith[k] * (double)Wv[k * NE + t];
      for (int k = 0; k < NE; ++k) acc2 += (double)sh.m.hcur[k] * (double)Wv[(NE + k) * NE + t];
      float mm = (float)acc2 + bv[t];
      sh.m.query[t] = sh.m.hbar[t] + mm;
    }
    __syncthreads();
  }
}

extern "C" void kernel_launch(void* const* d_in, const int* in_sizes, int n_in,
                              void* d_out, int out_size, void* d_ws, size_t ws_size,
                              hipStream_t stream) {
  const float* cv   = (const float*)d_in[0];
  const float* mask = (const float*)d_in[2];
  const float* liw  = (const float*)d_in[3];
  const float* Wc   = (const float*)d_in[4];
  const float* bc   = (const float*)d_in[5];
  const float* Wv   = (const float*)d_in[6];
  const float* bv   = (const float*)d_in[7];
  const float* Wq   = (const float*)d_in[8];
  const float* Wref = (const float*)d_in[9];
  const float* vv   = (const float*)d_in[10];
  (void)in_sizes; (void)n_in; (void)out_size;

  const size_t SZ_QQB = (size_t)NBATCH * NH * sizeof(double);     // 512 KB
  const size_t SZ_M   = (size_t)NE * NH * sizeof(float);          // 64 KB each
  const size_t SZ_QQ0 = (size_t)NBATCH * NH * sizeof(float);      // 256 KB
  const size_t SZ_A2  = (size_t)NBATCH * NS * NH * sizeof(double);// 134 MB
  const size_t need_min = SZ_QQB + 2 * SZ_M + SZ_QQ0 + 512;
  const size_t need_pre = need_min + SZ_A2;

  if (ws_size >= need_min) {
    char* p = (char*)d_ws;
    double* qqbase = (double*)p;            p += SZ_QQB;
    float*  M1T    = (float*)p;             p += SZ_M;
    float*  M2T    = (float*)p;             p += SZ_M;
    float*  qq0    = (float*)p;             p += SZ_QQ0;
    float*  rest0  = (float*)p;             p += 512;
    double* A2     = (double*)p;

    k1_mats<<<257, 128, 0, stream>>>(Wv, Wq, liw, bv, M1T, M2T, rest0);
    k2_base<<<NBATCH, 128, 0, stream>>>(cv, Wc, bc, bv, Wq, rest0, qqbase, qq0);
    if (ws_size >= need_pre) {
      k_a2v2<<<NBATCH * 8, 256, 0, stream>>>(cv, M2T, A2);
      decode_main<1><<<NBATCH, 512, 0, stream>>>(cv, mask, Wref, vv, qqbase, M1T,
                                                 M2T, qq0, A2, (float*)d_out);
    } else {
      decode_main<0><<<NBATCH, 512, 0, stream>>>(cv, mask, Wref, vv, qqbase, M1T,
                                                 M2T, qq0, nullptr, (float*)d_out);
    }
  } else {
    decoder_kernel_ref<<<NBATCH, 256, 0, stream>>>(cv, mask, liw, Wc, bc, Wv, bv,
                                                   Wq, Wref, vv, (float*)d_out);
  }
}

// Round 8
// 3162.858 us; speedup vs baseline: 2.2656x; 1.1344x over previous
//
#include <hip/hip_runtime.h>
#include <hip/hip_bf16.h>
#include <stdint.h>
#include <math.h>

#define NBATCH 512
#define NS 256
#define NE 128
#define NH 128
#define NSTEPS 255
#define NEGINF -1e8f
#define SENT_NEG -1e30f

// ---------------- threefry2x32 (partitionable path, verified r2..r7) ----------------
__device__ __forceinline__ uint32_t rotl32(uint32_t x, uint32_t r) {
  return (x << r) | (x >> (32u - r));
}

__device__ __forceinline__ void tf2x32(uint32_t k0, uint32_t k1,
                                       uint32_t x0, uint32_t x1,
                                       uint32_t& o0, uint32_t& o1) {
  uint32_t ks2 = k0 ^ k1 ^ 0x1BD11BDAu;
  x0 += k0; x1 += k1;
#define TF_R4(a,b,c,d) \
  x0 += x1; x1 = rotl32(x1,a); x1 ^= x0; \
  x0 += x1; x1 = rotl32(x1,b); x1 ^= x0; \
  x0 += x1; x1 = rotl32(x1,c); x1 ^= x0; \
  x0 += x1; x1 = rotl32(x1,d); x1 ^= x0;
  TF_R4(13,15,26,6)   x0 += k1;  x1 += ks2 + 1u;
  TF_R4(17,29,16,24)  x0 += ks2; x1 += k0 + 2u;
  TF_R4(13,15,26,6)   x0 += k0;  x1 += k1 + 3u;
  TF_R4(17,29,16,24)  x0 += k1;  x1 += ks2 + 4u;
  TF_R4(13,15,26,6)   x0 += ks2; x1 += k0 + 5u;
#undef TF_R4
  o0 = x0; o1 = x1;
}

__device__ __forceinline__ float gumbel_of(uint2 key, uint32_t j) {
  uint32_t o0, o1;
  tf2x32(key.x, key.y, 0u, j, o0, o1);
  uint32_t bits = o0 ^ o1;
  float f = __uint_as_float((bits >> 9) | 0x3f800000u) - 1.0f;
  float u = (f == 0.0f) ? 1.17549435e-38f : f;
  float l1 = -logf(u);
  return -logf(l1);
}

// tanh via hw exp2 + rcp + 1 Newton step (verified exact-index r3..r7)
__device__ __forceinline__ float nr_tanh(float x) {
  const float Chi = 2.8853900432586670f;
  const float Clo = 3.8519259822379735e-08f;
  float m = fmaf(x, Chi, x * Clo);
  m = fminf(m, 126.0f);
  float tt = __builtin_amdgcn_exp2f(m);
  float d  = tt + 1.0f;
  float r  = __builtin_amdgcn_rcpf(d);
  r = r * fmaf(-d, r, 2.0f);
  return fmaf(-2.0f, r, 1.0f);
}

// 32-wide f64 sub-dot of float4 arrays (MODE0 / step-0 paths)
__device__ __forceinline__ double dot32(const float4* __restrict__ a,
                                        const float4* __restrict__ bp) {
  double s = 0.0;
#pragma unroll
  for (int q = 0; q < 8; ++q) {
    float4 x = a[q], y = bp[q];
    s += (double)x.x * (double)y.x + (double)x.y * (double)y.y
       + (double)x.z * (double)y.z + (double)x.w * (double)y.w;
  }
  return s;
}

__device__ __forceinline__ double dot4d(float4 a, float4 b) {
  return ((double)a.x * (double)b.x + (double)a.y * (double)b.y)
       + ((double)a.z * (double)b.z + (double)a.w * (double)b.w);
}

// ======================= precompute kernels =======================
__global__ void k1_mats(const float* __restrict__ Wv, const float* __restrict__ Wq,
                        const float* __restrict__ liw, const float* __restrict__ bvv,
                        float* __restrict__ M1T, float* __restrict__ M2T,
                        float* __restrict__ rest0) {
  int e = blockIdx.x, h = threadIdx.x;
  __shared__ float wrow[NE];
  if (e < 256) {
    wrow[h] = Wv[e * NE + h];
    __syncthreads();
    double a = 0.0;
    for (int k = 0; k < NE; ++k) a += (double)wrow[k] * (double)Wq[k * NH + h];
    if (e < 128) M1T[h * NE + e] = (float)a;
    else         M2T[h * NE + (e - 128)] = (float)a;
  } else {
    double a = 0.0;
    for (int k = 0; k < 2 * NE; ++k) a += (double)liw[k] * (double)Wv[k * NE + h];
    rest0[h] = (float)a + bvv[h];
  }
}

__global__ void k2_base(const float* __restrict__ cv, const float* __restrict__ Wc,
                        const float* __restrict__ bc, const float* __restrict__ bvv,
                        const float* __restrict__ Wq, const float* __restrict__ rest0,
                        double* __restrict__ qqbase, float* __restrict__ qq0) {
  int b = blockIdx.x, h = threadIdx.x;
  int b256 = b << 8;
  __shared__ float meanL[NE], hbarL[NE];
  double ms = 0.0;
  for (int s = 0; s < NS; ++s) ms += (double)cv[((size_t)b256 + s) * NE + h];
  meanL[h] = (float)(ms * (1.0 / 256.0));
  __syncthreads();
  double a = 0.0;
  for (int e = 0; e < NE; ++e) a += (double)meanL[e] * (double)Wc[e * NE + h];
  hbarL[h] = (float)a + bc[h];
  __syncthreads();
  double ab = 0.0, a0 = 0.0;
  for (int k = 0; k < NE; ++k) {
    double w = (double)Wq[k * NH + h];
    ab += (double)(hbarL[k] + bvv[k]) * w;
    a0 += (double)(hbarL[k] + rest0[k]) * w;
  }
  qqbase[(size_t)b * NH + h] = ab;
  qq0[(size_t)b * NH + h] = (float)a0;
}

// k_a2v3: A2[b][s][h] = f64 dot(cv[b][s][:], M2T[h][:]).
// thread = (h = t>>1, khalf = t&1): 16 float4 of M2T in regs (no spill),
// 16B-aligned LDS rows (132-float stride), pair-combine via shfl_xor(1).
__global__ __launch_bounds__(256, 4)
void k_a2v3(const float* __restrict__ cv, const float* __restrict__ M2T,
            double* __restrict__ A2) {
  const int b  = blockIdx.x >> 3;
  const int s0 = (blockIdx.x & 7) << 5;      // 32 rows per block
  const int t  = threadIdx.x;
  const int h  = t >> 1;
  const int kh = t & 1;
  const int b256 = b << 8;
  __shared__ float cvS[32][132];              // 528B rows: float4-aligned
  for (int idx = t; idx < 32 * NE; idx += 256) {
    int r = idx >> 7, c = idx & 127;
    cvS[r][c] = cv[((size_t)(b256 + s0 + r)) * NE + c];
  }
  __syncthreads();
  float4 m2r[16];
  {
    const float4* m2p = (const float4*)(M2T + (size_t)h * NE + kh * 64);
#pragma unroll
    for (int q = 0; q < 16; ++q) m2r[q] = m2p[q];
  }
#pragma unroll 2
  for (int sLoc = 0; sLoc < 32; ++sLoc) {
    const float4* cr4 = ((const float4*)&cvS[sLoc][0]) + kh * 16;
    double c0 = 0.0, c1 = 0.0;
#pragma unroll
    for (int q = 0; q < 16; q += 2) {
      c0 += dot4d(cr4[q],     m2r[q]);
      c1 += dot4d(cr4[q + 1], m2r[q + 1]);
    }
    double s = c0 + c1;
    s += __shfl_xor(s, 1, 64);               // k-halves combine (exact, commutative)
    if (kh == 0)
      A2[((size_t)(b256 + s0 + sLoc)) * NH + h] = s;
  }
}

// ======================= main decode kernel =======================
struct MainSh {
  alignas(16) float  qq[NH];
  alignas(16) float  vvf[NH];
  alignas(8)  double partA[NS];
  float  logitArr[NS];
  alignas(8)  double base128[NH];
  uint2  keyL[NSTEPS];
  float  redV[8];
  float  redS[8];
  int    redI[8];
};

struct PreSh {
  float cvS[NS][33];
  float wS[32][NH];
};

template <int MODE>   // 0: stream M2T per step; 1: A2 precomputed
__global__ __launch_bounds__(512, 4)
void decode_main(const float* __restrict__ cv,
                 const float* __restrict__ mask_in,
                 const float* __restrict__ Wref,
                 const float* __restrict__ vvec,
                 const double* __restrict__ qqbase,
                 const float* __restrict__ M1T,
                 const float* __restrict__ M2T,
                 const float* __restrict__ qq0,
                 const double* __restrict__ A2,
                 float* __restrict__ out) {
  const int b = blockIdx.x;
  const int t = threadIdx.x;
  const int b256 = b << 8;
  // SIMD-balance rotation: chunk->wave shifted per block so the two
  // co-resident blocks' active waves land on different SIMDs as nA shrinks.
  const int chunk = (((t >> 6) & 3) + b) & 3;
  const int i = (chunk << 6) | (t & 63);     // list position (pair index)
  const int halfo = t >> 8;
  const int hb = halfo << 6;

  __shared__ union { PreSh pre; MainSh m; } sh;
  __shared__ short rowIdA[NS], rowIdB[NS], posA[NS], posB[NS];
  __shared__ int nActSh[2], jSh[2], tmp8[4];
  __shared__ alignas(16) float refScratch[NE];

  // ---------- build initial active-row list ----------
  bool act0 = false;
  if (t < NS) {
    act0 = !((t == 0) || (mask_in[(size_t)b256 + t] > 0.0f));
    uint64_t mb = __ballot(act0);
    int lane = t & 63, w = t >> 6;
    int pre = __popcll(mb & (((uint64_t)1 << lane) - 1));
    if (lane == 0) tmp8[w] = (int)__popcll(mb);
    posA[t] = (short)pre;
  }
  __syncthreads();
  if (t < NS) {
    int base = 0;
    for (int k = 0; k < (t >> 6); ++k) base += tmp8[k];
    int p = base + (int)posA[t];
    if (act0) rowIdA[p] = (short)t;
    posA[t] = (short)p;
  }
  if (t == 0) {
    nActSh[0] = tmp8[0] + tmp8[1] + tmp8[2] + tmp8[3];
    jSh[0] = -1;
  }
  __syncthreads();
  const int nAct0 = nActSh[0];

  // ---------- Phase 1: refr = ref[myRow0][hb..hb+64) (bit-identical chunking) ----------
  const int myRow0 = (i < nAct0) ? (int)rowIdA[i] : 0;
  float refr[64];
#pragma unroll
  for (int j = 0; j < 64; ++j) refr[j] = 0.0f;

  for (int ec = 0; ec < 4; ++ec) {
    __syncthreads();
    for (int ii = t; ii < 32 * NH; ii += 512) {
      int r = ii >> 7, c = ii & 127;
      sh.pre.wS[r][c] = Wref[(ec * 32 + r) * NH + c];
    }
    for (int ii = t; ii < NS * 32; ii += 512) {
      int r = ii >> 5, c = ii & 31;
      sh.pre.cvS[r][c] = cv[((size_t)b256 + r) * NE + ec * 32 + c];
    }
    __syncthreads();
    for (int hc = 0; hc < 8; ++hc) {
      double a[8] = {0,0,0,0,0,0,0,0};
      for (int e = 0; e < 32; ++e) {
        double cd = (double)sh.pre.cvS[myRow0][e];
        const float* wp = &sh.pre.wS[e][hb + hc * 8];
#pragma unroll
        for (int j = 0; j < 8; ++j) a[j] += cd * (double)wp[j];
      }
#pragma unroll
      for (int j = 0; j < 8; ++j) refr[hc * 8 + j] += (float)a[j];
    }
  }
  __syncthreads();  // pre dead, m live

  // ---------- prologue ----------
  if (t < NSTEPS) {
    uint32_t o0, o1;
    tf2x32(0u, 42u, 0u, (uint32_t)t, o0, o1);
    sh.m.keyL[t] = make_uint2(o0, o1);
  }
  if (t < NH) {
    sh.m.vvf[t] = vvec[t];
    sh.m.qq[t] = qq0[(size_t)b * NH + t];
  }
  __syncthreads();

  // step-0 gumbel, pipelined in register g
  float g = 0.0f;
  if (halfo && i < nAct0)
    g = gumbel_of(sh.m.keyL[0], (uint32_t)(b256 + myRow0));

  // ---------- 255 decode steps ----------
  for (int step = 0; step < NSTEPS; ++step) {
    const int cur = step & 1;
    const short* rowId_c = cur ? rowIdB : rowIdA;
    const short* pos_c   = cur ? posB   : posA;
    short* rowId_n = cur ? rowIdA : rowIdB;
    short* pos_n   = cur ? posA   : posB;
    const int nA    = nActSh[cur];
    const int jPrev = jSh[cur];
    const bool active = (i < nA);
    const int myRow = active ? (int)rowId_c[i] : 0;

    // adoption: pair that inherited the donor row reloads its refr slice
    if (jPrev >= 0 && i == jPrev) {
      const float4* rs4 = (const float4*)(refScratch + hb);
#pragma unroll
      for (int q = 0; q < 16; ++q) {
        float4 v4 = rs4[q];
        refr[4 * q + 0] = v4.x; refr[4 * q + 1] = v4.y;
        refr[4 * q + 2] = v4.z; refr[4 * q + 3] = v4.w;
      }
    }

    // tanh partial over this thread's 64-wide h-slice
    double accH = 0.0;
    if (active) {
      double a0 = 0, a1 = 0, a2 = 0, a3 = 0;
      const float4* qq4 = (const float4*)(sh.m.qq + hb);
      const float4* vv4 = (const float4*)(sh.m.vvf + hb);
#pragma unroll
      for (int q = 0; q < 16; ++q) {
        float4 qv = qq4[q];
        float4 wv = vv4[q];
        a0 += (double)nr_tanh(qv.x + refr[4 * q + 0]) * (double)wv.x;
        a1 += (double)nr_tanh(qv.y + refr[4 * q + 1]) * (double)wv.y;
        a2 += (double)nr_tanh(qv.z + refr[4 * q + 2]) * (double)wv.z;
        a3 += (double)nr_tanh(qv.w + refr[4 * q + 3]) * (double)wv.w;
      }
      accH = (a0 + a1) + (a2 + a3);
      if (!halfo) sh.m.partA[i] = accH;
    }
    __syncthreads();  // B1

    if (halfo) {
      float val = SENT_NEG; int vRow = 0x7fffffff; float term = 0.0f;
      if (active) {
        float u_ = (float)(sh.m.partA[i] + accH);
        float logit = 10.0f * (float)tanh((double)u_);
        sh.m.logitArr[myRow] = logit;
        term = expf(logit);
        val = logit + g;
        vRow = myRow;
      }
      float bvv = val; int bR = vRow; float bss = term;
#pragma unroll
      for (int mm = 1; mm <= 32; mm <<= 1) {
        float ov = __shfl_xor(bvv, mm, 64);
        int   oR = __shfl_xor(bR,  mm, 64);
        float os = __shfl_xor(bss, mm, 64);
        bss += os;
        if (ov > bvv || (ov == bvv && oR < bR)) { bvv = ov; bR = oR; }
      }
      if ((t & 63) == 0) {
        int w = t >> 6;   // 4..7
        sh.m.redV[w] = bvv; sh.m.redI[w] = bR; sh.m.redS[w] = bss;
      }
    }
    __syncthreads();  // B2

    float BV = sh.m.redV[4]; int BR = sh.m.redI[4];
#pragma unroll
    for (int k = 5; k < 8; ++k) {
      float ov = sh.m.redV[k]; int oR = sh.m.redI[k];
      if (ov > BV || (ov == BV && oR < BR)) { BV = ov; BR = oR; }
    }
    if ((unsigned)BR > 255u) BR = 0;
    const int BI = BR;
    const int jj = (int)pos_c[BI];

    // early-issue A2 row load (MODE 1, steps >= 1)
    double a2v = 0.0;
    if (MODE == 1 && step > 0 && step + 1 < NSTEPS && t < NH)
      a2v = A2[(size_t)(b256 + BI) * NH + t];

    if (t == 0) {
      float SS = (sh.m.redS[4] + sh.m.redS[5]) + (sh.m.redS[6] + sh.m.redS[7]);
      float lp = sh.m.logitArr[BI] - (float)log((double)SS);
      out[(size_t)b * NSTEPS + step] = (float)BI;
      out[(size_t)NBATCH * NSTEPS + (size_t)b * NSTEPS + step] = lp;
      nActSh[cur ^ 1] = nA - 1;
      jSh[cur ^ 1] = (jj < nA - 1) ? jj : -1;
    }

    if (t < NS) {
      int donorRow = (int)rowId_c[nA - 1];
      short rid = (t == jj) ? (short)donorRow : rowId_c[t];
      rowId_n[t] = rid;
      if (t < nA - 1) pos_n[rid] = (short)t;
    }
    if (jj < nA - 1 && i == nA - 1) {
      float4* rs4 = (float4*)(refScratch + hb);
#pragma unroll
      for (int q = 0; q < 16; ++q)
        rs4[q] = make_float4(refr[4 * q + 0], refr[4 * q + 1],
                             refr[4 * q + 2], refr[4 * q + 3]);
    }

    // next-step gumbel (upper threads; overlaps qq update / A2 latency)
    if (halfo && step + 1 < NSTEPS) {
      int nA_next = nA - 1;
      if (i < nA_next) {
        int ridN = (i == jj) ? (int)rowId_c[nA - 1] : myRow;
        g = gumbel_of(sh.m.keyL[step + 1], (uint32_t)(b256 + ridN));
      }
    }

    // ---- qq update ----
    if (step + 1 < NSTEPS) {
      if (MODE == 1) {
        if (step == 0) {
          const int hq = t >> 2, kq = t & 3;
          const float4* hrow = (const float4*)(cv + (size_t)(b256 + BI) * NE + kq * 32);
          const float4* m1p  = (const float4*)(M1T + (size_t)hq * NE + kq * 32);
          double am = dot32(hrow, m1p);
          am += __shfl_xor(am, 1, 64);
          am += __shfl_xor(am, 2, 64);
          if (kq == 0) {
            double dbase = qqbase[(size_t)b * NH + hq] + am;
            sh.m.base128[hq] = dbase;
            sh.m.qq[hq] = (float)(dbase + A2[(size_t)(b256 + BI) * NH + hq]);
          }
        } else if (t < NH) {
          sh.m.qq[t] = (float)(sh.m.base128[t] + a2v);
        }
      } else {
        const int hq = t >> 2, kq = t & 3;
        const float4* hrow = (const float4*)(cv + (size_t)(b256 + BI) * NE + kq * 32);
        const float4* m2p  = (const float4*)(M2T + (size_t)hq * NE + kq * 32);
        double a2 = dot32(hrow, m2p);
        a2 += __shfl_xor(a2, 1, 64);
        a2 += __shfl_xor(a2, 2, 64);
        if (step == 0) {
          const float4* m1p = (const float4*)(M1T + (size_t)hq * NE + kq * 32);
          double am = dot32(hrow, m1p);
          am += __shfl_xor(am, 1, 64);
          am += __shfl_xor(am, 2, 64);
          if (kq == 0) {
            double dbase = qqbase[(size_t)b * NH + hq] + am;
            sh.m.base128[hq] = dbase;
            sh.m.qq[hq] = (float)(dbase + a2);
          }
        } else if (kq == 0) {
          sh.m.qq[hq] = (float)(sh.m.base128[hq] + a2);
        }
      }
    }
    __syncthreads();  // B3
  }
}

// ======================= round-2 passing kernel (no-ws fallback, unchanged) ==========
__device__ __forceinline__ float fast_tanh_ref(float x) {
  const float Chi = 2.8853900432586670f;
  const float Clo = 3.8519259822379735e-08f;
  float m = fmaf(x, Chi, x * Clo);
  float tt = exp2f(m);
  return 1.0f - 2.0f / (tt + 1.0f);
}

struct MainShR {
  float  query[NE];
  float  qq[NH];
  float  hbar[NE];
  float  inith[NE];
  float  hcur[NE];
  alignas(16) double vvd[NH];
  float  logitArr[NS];
  float  maskArr[NS];
  uint2  keyL[NSTEPS];
  float  meanv[NE];
  float  redV[4];
  int    redI[4];
  double redS[4];
  int    idxSh;
};
struct PreShR {
  float cvS[NS][33];
  float wS[32][NH];
};

__global__ __launch_bounds__(256, 2)
void decoder_kernel_ref(const float* __restrict__ cv, const float* __restrict__ mask_in,
                        const float* __restrict__ liw, const float* __restrict__ Wc,
                        const float* __restrict__ bc, const float* __restrict__ Wv,
                        const float* __restrict__ bv, const float* __restrict__ Wq,
                        const float* __restrict__ Wref, const float* __restrict__ vvec,
                        float* __restrict__ out) {
  const int b = blockIdx.x;
  const int t = threadIdx.x;
  const int b256 = b << 8;
  __shared__ union { PreShR pre; MainShR m; } sh;

  float refr[NH];
#pragma unroll
  for (int h = 0; h < NH; ++h) refr[h] = 0.0f;
  for (int ec = 0; ec < 4; ++ec) {
    const int e0 = ec * 32;
    __syncthreads();
    for (int i = t; i < 32 * NH; i += 256) {
      int r = i >> 7, h = i & 127;
      sh.pre.wS[r][h] = Wref[(e0 + r) * NH + h];
    }
    for (int i = t; i < NS * 32; i += 256) {
      int s2 = i >> 5, j = i & 31;
      sh.pre.cvS[s2][j] = cv[((size_t)b256 + s2) * NE + e0 + j];
    }
    __syncthreads();
#pragma unroll
    for (int hc = 0; hc < 16; ++hc) {
      double a[8] = {0,0,0,0,0,0,0,0};
      for (int e = 0; e < 32; ++e) {
        double cd = (double)sh.pre.cvS[t][e];
#pragma unroll
        for (int j = 0; j < 8; ++j) a[j] += cd * (double)sh.pre.wS[e][hc * 8 + j];
      }
#pragma unroll
      for (int j = 0; j < 8; ++j) refr[hc * 8 + j] += (float)a[j];
    }
  }
  __syncthreads();

  if (t < NSTEPS) {
    uint32_t o0, o1;
    tf2x32(0u, 42u, 0u, (uint32_t)t, o0, o1);
    sh.m.keyL[t] = make_uint2(o0, o1);
  }
  if (t < NH) sh.m.vvd[t] = (double)vvec[t];
  sh.m.maskArr[t] = (mask_in[(size_t)b256 + t] > 0.0f || t == 0) ? 1.0f : 0.0f;
  if (t < NE) {
    double s64 = 0.0;
    for (int s2 = 0; s2 < NS; ++s2) s64 += (double)cv[((size_t)b256 + s2) * NE + t];
    sh.m.meanv[t] = (float)(s64 * (1.0 / 256.0));
  }
  __syncthreads();
  if (t < NE) {
    double acc = 0.0;
    for (int e = 0; e < NE; ++e) acc += (double)sh.m.meanv[e] * (double)Wc[e * NE + t];
    float hbv = (float)acc + bc[t];
    sh.m.hbar[t] = hbv;
    double acc2 = 0.0;
    for (int k = 0; k < 2 * NE; ++k) acc2 += (double)liw[k] * (double)Wv[k * NE + t];
    float r0 = (float)acc2 + bv[t];
    sh.m.query[t] = hbv + r0;
  }
  __syncthreads();

  for (int step = 0; step < NSTEPS; ++step) {
    if (t < NH) {
      double acc = 0.0;
      for (int k = 0; k < NE; ++k) acc += (double)sh.m.query[k] * (double)Wq[k * NH + t];
      sh.m.qq[t] = (float)acc;
    }
    __syncthreads();

    float logit;
    bool masked = (sh.m.maskArr[t] != 0.0f);
    if (!masked) {
      double a0 = 0.0, a1 = 0.0, a2 = 0.0, a3 = 0.0;
      const float4*  qq4 = (const float4*)sh.m.qq;
      const double2* vv2 = (const double2*)sh.m.vvd;
#pragma unroll
      for (int h4 = 0; h4 < 32; ++h4) {
        float4  q  = qq4[h4];
        double2 va = vv2[2 * h4];
        double2 vb = vv2[2 * h4 + 1];
        a0 += (double)fast_tanh_ref(q.x + refr[4 * h4 + 0]) * va.x;
        a1 += (double)fast_tanh_ref(q.y + refr[4 * h4 + 1]) * va.y;
        a2 += (double)fast_tanh_ref(q.z + refr[4 * h4 + 2]) * vb.x;
        a3 += (double)fast_tanh_ref(q.w + refr[4 * h4 + 3]) * vb.y;
      }
      float u_ = (float)((a0 + a1) + (a2 + a3));
      logit = 10.0f * (float)tanh((double)u_);
    } else {
      logit = NEGINF;
    }
    sh.m.logitArr[t] = logit;

    uint2 key = sh.m.keyL[step];
    uint32_t j = (uint32_t)(b256 + t);
    uint32_t o0, o1;
    tf2x32(key.x, key.y, 0u, j, o0, o1);
    uint32_t bits = o0 ^ o1;
    float f = __uint_as_float((bits >> 9) | 0x3f800000u) - 1.0f;
    float u = (f == 0.0f) ? 1.17549435e-38f : f;
    float l1 = (float)(-log((double)u));
    float g  = (float)(-log((double)l1));
    float val = logit + g;
    double term = exp((double)logit);

    float bv_ = val; int bi = t; double bs = term;
#pragma unroll
    for (int m = 1; m <= 32; m <<= 1) {
      float  ov = __shfl_xor(bv_, m, 64);
      int    oi = __shfl_xor(bi,  m, 64);
      double os = __shfl_xor(bs,  m, 64);
      if (ov > bv_ || (ov == bv_ && oi < bi)) { bv_ = ov; bi = oi; }
      bs += os;
    }
    int w = t >> 6;
    if ((t & 63) == 0) { sh.m.redV[w] = bv_; sh.m.redI[w] = bi; sh.m.redS[w] = bs; }
    __syncthreads();

    if (t == 0) {
      float BV = sh.m.redV[0]; int BI = sh.m.redI[0];
      for (int k = 1; k < 4; ++k) {
        float ov = sh.m.redV[k]; int oi = sh.m.redI[k];
        if (ov > BV || (ov == BV && oi < BI)) { BV = ov; BI = oi; }
      }
      double SS = ((sh.m.redS[0] + sh.m.redS[1]) + (sh.m.redS[2] + sh.m.redS[3]));
      sh.m.idxSh = BI;
      float lp = sh.m.logitArr[BI] - (float)log(SS);
      out[(size_t)b * NSTEPS + step] = (float)BI;
      out[(size_t)NBATCH * NSTEPS + (size_t)b * NSTEPS + step] = lp;
    }
    __syncthreads();

    int idx = sh.m.idxSh;
    if (t == idx) sh.m.maskArr[t] = 1.0f;
    if (t < NE) {
      float hc = cv[((size_t)b256 + idx) * NE + t];
      sh.m.hcur[t] = hc;
      if (step == 0) sh.m.inith[t] = hc;
    }
    __syncthreads();

    if (t < NE) {
      double acc2 = 0.0;
      for (int k = 0; k < NE; ++k) acc2 += (double)sh.m.inith[k] * (double)Wv[k * NE + t];
      for (int k = 0; k < NE; ++k) acc2 += (double)sh.m.hcur[k] * (double)Wv[(NE + k) * NE + t];
      float mm = (float)acc2 + bv[t];
      sh.m.query[t] = sh.m.hbar[t] + mm;
    }
    __syncthreads();
  }
}

extern "C" void kernel_launch(void* const* d_in, const int* in_sizes, int n_in,
                              void* d_out, int out_size, void* d_ws, size_t ws_size,
                              hipStream_t stream) {
  const float* cv   = (const float*)d_in[0];
  const float* mask = (const float*)d_in[2];
  const float* liw  = (const float*)d_in[3];
  const float* Wc   = (const float*)d_in[4];
  const float* bc   = (const float*)d_in[5];
  const float* Wv   = (const float*)d_in[6];
  const float* bv   = (const float*)d_in[7];
  const float* Wq   = (const float*)d_in[8];
  const float* Wref = (const float*)d_in[9];
  const float* vv   = (const float*)d_in[10];
  (void)in_sizes; (void)n_in; (void)out_size;

  const size_t SZ_QQB = (size_t)NBATCH * NH * sizeof(double);     // 512 KB
  const size_t SZ_M   = (size_t)NE * NH * sizeof(float);          // 64 KB each
  const size_t SZ_QQ0 = (size_t)NBATCH * NH * sizeof(float);      // 256 KB
  const size_t SZ_A2  = (size_t)NBATCH * NS * NH * sizeof(double);// 134 MB
  const size_t need_min = SZ_QQB + 2 * SZ_M + SZ_QQ0 + 512;
  const size_t need_pre = need_min + SZ_A2;

  if (ws_size >= need_min) {
    char* p = (char*)d_ws;
    double* qqbase = (double*)p;            p += SZ_QQB;
    float*  M1T    = (float*)p;             p += SZ_M;
    float*  M2T    = (float*)p;             p += SZ_M;
    float*  qq0    = (float*)p;             p += SZ_QQ0;
    float*  rest0  = (float*)p;             p += 512;
    double* A2     = (double*)p;

    k1_mats<<<257, 128, 0, stream>>>(Wv, Wq, liw, bv, M1T, M2T, rest0);
    k2_base<<<NBATCH, 128, 0, stream>>>(cv, Wc, bc, bv, Wq, rest0, qqbase, qq0);
    if (ws_size >= need_pre) {
      k_a2v3<<<NBATCH * 8, 256, 0, stream>>>(cv, M2T, A2);
      decode_main<1><<<NBATCH, 512, 0, stream>>>(cv, mask, Wref, vv, qqbase, M1T,
                                                 M2T, qq0, A2, (float*)d_out);
    } else {
      decode_main<0><<<NBATCH, 512, 0, stream>>>(cv, mask, Wref, vv, qqbase, M1T,
                                                 M2T, qq0, nullptr, (float*)d_out);
    }
  } else {
    decoder_kernel_ref<<<NBATCH, 256, 0, stream>>>(cv, mask, liw, Wc, bc, Wv, bv,
                                                   Wq, Wref, vv, (float*)d_out);
  }
}

// Round 9
// 3029.144 us; speedup vs baseline: 2.3656x; 1.0441x over previous
//
#include <hip/hip_runtime.h>
#include <hip/hip_bf16.h>
#include <stdint.h>
#include <math.h>

#define NBATCH 512
#define NS 256
#define NE 128
#define NH 128
#define NSTEPS 255
#define NEGINF -1e8f
#define SENT_NEG -1e30f

// ---------------- threefry2x32 (partitionable path, verified r2..r8) ----------------
__device__ __forceinline__ uint32_t rotl32(uint32_t x, uint32_t r) {
  return (x << r) | (x >> (32u - r));
}

__device__ __forceinline__ void tf2x32(uint32_t k0, uint32_t k1,
                                       uint32_t x0, uint32_t x1,
                                       uint32_t& o0, uint32_t& o1) {
  uint32_t ks2 = k0 ^ k1 ^ 0x1BD11BDAu;
  x0 += k0; x1 += k1;
#define TF_R4(a,b,c,d) \
  x0 += x1; x1 = rotl32(x1,a); x1 ^= x0; \
  x0 += x1; x1 = rotl32(x1,b); x1 ^= x0; \
  x0 += x1; x1 = rotl32(x1,c); x1 ^= x0; \
  x0 += x1; x1 = rotl32(x1,d); x1 ^= x0;
  TF_R4(13,15,26,6)   x0 += k1;  x1 += ks2 + 1u;
  TF_R4(17,29,16,24)  x0 += ks2; x1 += k0 + 2u;
  TF_R4(13,15,26,6)   x0 += k0;  x1 += k1 + 3u;
  TF_R4(17,29,16,24)  x0 += k1;  x1 += ks2 + 4u;
  TF_R4(13,15,26,6)   x0 += ks2; x1 += k0 + 5u;
#undef TF_R4
  o0 = x0; o1 = x1;
}

__device__ __forceinline__ float gumbel_of(uint2 key, uint32_t j) {
  uint32_t o0, o1;
  tf2x32(key.x, key.y, 0u, j, o0, o1);
  uint32_t bits = o0 ^ o1;
  float f = __uint_as_float((bits >> 9) | 0x3f800000u) - 1.0f;
  float u = (f == 0.0f) ? 1.17549435e-38f : f;
  float l1 = -logf(u);
  return -logf(l1);
}

// tanh via hw exp2 + rcp + 1 Newton step (verified exact-index r3..r8)
__device__ __forceinline__ float nr_tanh(float x) {
  const float Chi = 2.8853900432586670f;
  const float Clo = 3.8519259822379735e-08f;
  float m = fmaf(x, Chi, x * Clo);
  m = fminf(m, 126.0f);
  float tt = __builtin_amdgcn_exp2f(m);
  float d  = tt + 1.0f;
  float r  = __builtin_amdgcn_rcpf(d);
  r = r * fmaf(-d, r, 2.0f);
  return fmaf(-2.0f, r, 1.0f);
}

// 32-wide f64 sub-dot of float4 arrays (MODE0 / step-0 paths)
__device__ __forceinline__ double dot32(const float4* __restrict__ a,
                                        const float4* __restrict__ bp) {
  double s = 0.0;
#pragma unroll
  for (int q = 0; q < 8; ++q) {
    float4 x = a[q], y = bp[q];
    s += (double)x.x * (double)y.x + (double)x.y * (double)y.y
       + (double)x.z * (double)y.z + (double)x.w * (double)y.w;
  }
  return s;
}

__device__ __forceinline__ double dot4d(float4 a, float4 b) {
  return ((double)a.x * (double)b.x + (double)a.y * (double)b.y)
       + ((double)a.z * (double)b.z + (double)a.w * (double)b.w);
}

// ======================= precompute kernels (unchanged from r8) =======================
__global__ void k1_mats(const float* __restrict__ Wv, const float* __restrict__ Wq,
                        const float* __restrict__ liw, const float* __restrict__ bvv,
                        float* __restrict__ M1T, float* __restrict__ M2T,
                        float* __restrict__ rest0) {
  int e = blockIdx.x, h = threadIdx.x;
  __shared__ float wrow[NE];
  if (e < 256) {
    wrow[h] = Wv[e * NE + h];
    __syncthreads();
    double a = 0.0;
    for (int k = 0; k < NE; ++k) a += (double)wrow[k] * (double)Wq[k * NH + h];
    if (e < 128) M1T[h * NE + e] = (float)a;
    else         M2T[h * NE + (e - 128)] = (float)a;
  } else {
    double a = 0.0;
    for (int k = 0; k < 2 * NE; ++k) a += (double)liw[k] * (double)Wv[k * NE + h];
    rest0[h] = (float)a + bvv[h];
  }
}

__global__ void k2_base(const float* __restrict__ cv, const float* __restrict__ Wc,
                        const float* __restrict__ bc, const float* __restrict__ bvv,
                        const float* __restrict__ Wq, const float* __restrict__ rest0,
                        double* __restrict__ qqbase, float* __restrict__ qq0) {
  int b = blockIdx.x, h = threadIdx.x;
  int b256 = b << 8;
  __shared__ float meanL[NE], hbarL[NE];
  double ms = 0.0;
  for (int s = 0; s < NS; ++s) ms += (double)cv[((size_t)b256 + s) * NE + h];
  meanL[h] = (float)(ms * (1.0 / 256.0));
  __syncthreads();
  double a = 0.0;
  for (int e = 0; e < NE; ++e) a += (double)meanL[e] * (double)Wc[e * NE + h];
  hbarL[h] = (float)a + bc[h];
  __syncthreads();
  double ab = 0.0, a0 = 0.0;
  for (int k = 0; k < NE; ++k) {
    double w = (double)Wq[k * NH + h];
    ab += (double)(hbarL[k] + bvv[k]) * w;
    a0 += (double)(hbarL[k] + rest0[k]) * w;
  }
  qqbase[(size_t)b * NH + h] = ab;
  qq0[(size_t)b * NH + h] = (float)a0;
}

__global__ __launch_bounds__(256, 4)
void k_a2v3(const float* __restrict__ cv, const float* __restrict__ M2T,
            double* __restrict__ A2) {
  const int b  = blockIdx.x >> 3;
  const int s0 = (blockIdx.x & 7) << 5;
  const int t  = threadIdx.x;
  const int h  = t >> 1;
  const int kh = t & 1;
  const int b256 = b << 8;
  __shared__ float cvS[32][132];
  for (int idx = t; idx < 32 * NE; idx += 256) {
    int r = idx >> 7, c = idx & 127;
    cvS[r][c] = cv[((size_t)(b256 + s0 + r)) * NE + c];
  }
  __syncthreads();
  float4 m2r[16];
  {
    const float4* m2p = (const float4*)(M2T + (size_t)h * NE + kh * 64);
#pragma unroll
    for (int q = 0; q < 16; ++q) m2r[q] = m2p[q];
  }
#pragma unroll 2
  for (int sLoc = 0; sLoc < 32; ++sLoc) {
    const float4* cr4 = ((const float4*)&cvS[sLoc][0]) + kh * 16;
    double c0 = 0.0, c1 = 0.0;
#pragma unroll
    for (int q = 0; q < 16; q += 2) {
      c0 += dot4d(cr4[q],     m2r[q]);
      c1 += dot4d(cr4[q + 1], m2r[q + 1]);
    }
    double s = c0 + c1;
    s += __shfl_xor(s, 1, 64);
    if (kh == 0)
      A2[((size_t)(b256 + s0 + sLoc)) * NH + h] = s;
  }
}

// ======================= main decode kernel =======================
struct MainSh {
  alignas(16) float  qq[NH];
  alignas(16) float  vvf[NH];
  float  logitArr[NS];
  alignas(8)  double base128[NH];
  uint2  keyL[NSTEPS];
  float  redV[8];
  float  redS[8];
  int    redI[8];
};

struct PreSh {
  float cvS[NS][33];
  float wS[32][NH];
};

template <int MODE>   // 0: stream M2T per step; 1: A2 precomputed
__global__ __launch_bounds__(512, 4)
void decode_main(const float* __restrict__ cv,
                 const float* __restrict__ mask_in,
                 const float* __restrict__ Wref,
                 const float* __restrict__ vvec,
                 const double* __restrict__ qqbase,
                 const float* __restrict__ M1T,
                 const float* __restrict__ M2T,
                 const float* __restrict__ qq0,
                 const double* __restrict__ A2,
                 float* __restrict__ out) {
  const int b = blockIdx.x;
  const int t = threadIdx.x;
  const int b256 = b << 8;
  const int w = t >> 6, l = t & 63;
  // pair-in-wave layout: the two h-halves of a row are ADJACENT LANES,
  // so the half-combine is one shfl_xor(1) -- no LDS, no barrier.
  const int i = (w << 5) | (l >> 1);     // list position
  const int hHalf = l & 1;
  const int hb = hHalf << 6;

  __shared__ union { PreSh pre; MainSh m; } sh;
  __shared__ short rowIdA[NS], rowIdB[NS], posA[NS], posB[NS];
  __shared__ int nActSh[2], jSh[2], tmp8[4];
  __shared__ alignas(16) float refScratch[NE];

  // ---------- build initial active-row list ----------
  bool act0 = false;
  if (t < NS) {
    act0 = !((t == 0) || (mask_in[(size_t)b256 + t] > 0.0f));
    uint64_t mb = __ballot(act0);
    int lane = t & 63, wv = t >> 6;
    int pre = __popcll(mb & (((uint64_t)1 << lane) - 1));
    if (lane == 0) tmp8[wv] = (int)__popcll(mb);
    posA[t] = (short)pre;
  }
  __syncthreads();
  if (t < NS) {
    int base = 0;
    for (int k = 0; k < (t >> 6); ++k) base += tmp8[k];
    int p = base + (int)posA[t];
    if (act0) rowIdA[p] = (short)t;
    posA[t] = (short)p;
  }
  if (t == 0) {
    nActSh[0] = tmp8[0] + tmp8[1] + tmp8[2] + tmp8[3];
    jSh[0] = -1;
  }
  __syncthreads();
  const int nAct0 = nActSh[0];

  // ---------- Phase 1: refr = ref[myRow0][hb..hb+64) (bit-identical chunking) ----------
  const int myRow0 = (i < nAct0) ? (int)rowIdA[i] : 0;
  float refr[64];
#pragma unroll
  for (int j = 0; j < 64; ++j) refr[j] = 0.0f;

  for (int ec = 0; ec < 4; ++ec) {
    __syncthreads();
    for (int ii = t; ii < 32 * NH; ii += 512) {
      int r = ii >> 7, c = ii & 127;
      sh.pre.wS[r][c] = Wref[(ec * 32 + r) * NH + c];
    }
    for (int ii = t; ii < NS * 32; ii += 512) {
      int r = ii >> 5, c = ii & 31;
      sh.pre.cvS[r][c] = cv[((size_t)b256 + r) * NE + ec * 32 + c];
    }
    __syncthreads();
    for (int hc = 0; hc < 8; ++hc) {
      double a[8] = {0,0,0,0,0,0,0,0};
      for (int e = 0; e < 32; ++e) {
        double cd = (double)sh.pre.cvS[myRow0][e];
        const float* wp = &sh.pre.wS[e][hb + hc * 8];
#pragma unroll
        for (int j = 0; j < 8; ++j) a[j] += cd * (double)wp[j];
      }
#pragma unroll
      for (int j = 0; j < 8; ++j) refr[hc * 8 + j] += (float)a[j];
    }
  }
  __syncthreads();  // pre dead, m live

  // ---------- prologue ----------
  if (t < NSTEPS) {
    uint32_t o0, o1;
    tf2x32(0u, 42u, 0u, (uint32_t)t, o0, o1);
    sh.m.keyL[t] = make_uint2(o0, o1);
  }
  if (t < NH) {
    sh.m.vvf[t] = vvec[t];
    sh.m.qq[t] = qq0[(size_t)b * NH + t];
  }
  __syncthreads();

  // step-0 gumbel (both lanes of each pair: same row, same value)
  float g = 0.0f;
  if (i < nAct0)
    g = gumbel_of(sh.m.keyL[0], (uint32_t)(b256 + myRow0));

  // ---------- 255 decode steps ----------
  for (int step = 0; step < NSTEPS; ++step) {
    const int cur = step & 1;
    const short* rowId_c = cur ? rowIdB : rowIdA;
    const short* pos_c   = cur ? posB   : posA;
    short* rowId_n = cur ? rowIdA : rowIdB;
    short* pos_n   = cur ? posA   : posB;
    const int nA    = nActSh[cur];
    const int jPrev = jSh[cur];
    const bool active = (i < nA);
    const int myRow = active ? (int)rowId_c[i] : 0;

    // adoption: pair that inherited the donor row reloads its refr slice
    if (jPrev >= 0 && i == jPrev) {
      const float4* rs4 = (const float4*)(refScratch + hb);
#pragma unroll
      for (int q = 0; q < 16; ++q) {
        float4 v4 = rs4[q];
        refr[4 * q + 0] = v4.x; refr[4 * q + 1] = v4.y;
        refr[4 * q + 2] = v4.z; refr[4 * q + 3] = v4.w;
      }
    }

    // tanh partial over this thread's 64-wide h-slice
    double accH = 0.0;
    if (active) {
      double a0 = 0, a1 = 0, a2 = 0, a3 = 0;
      const float4* qq4 = (const float4*)(sh.m.qq + hb);
      const float4* vv4 = (const float4*)(sh.m.vvf + hb);
#pragma unroll
      for (int q = 0; q < 16; ++q) {
        float4 qv = qq4[q];
        float4 wv = vv4[q];
        a0 += (double)nr_tanh(qv.x + refr[4 * q + 0]) * (double)wv.x;
        a1 += (double)nr_tanh(qv.y + refr[4 * q + 1]) * (double)wv.y;
        a2 += (double)nr_tanh(qv.z + refr[4 * q + 2]) * (double)wv.z;
        a3 += (double)nr_tanh(qv.w + refr[4 * q + 3]) * (double)wv.w;
      }
      accH = (a0 + a1) + (a2 + a3);
    }
    // pair combine: low half + high half, exactly as before (low first)
    double other = __shfl_xor(accH, 1, 64);
    float val = SENT_NEG; int vRow = 0x7fffffff; float term = 0.0f;
    if (active) {
      double tot = hHalf ? (other + accH) : (accH + other);  // = low + high
      float u_ = (float)tot;
      float logit = 10.0f * (float)tanh((double)u_);
      if (!hHalf) {
        sh.m.logitArr[myRow] = logit;
        term = expf(logit);          // counted once per row in the lse sum
      }
      val = logit + g;
      vRow = myRow;
    }

    // wave reduce: 32 rows per wave (entries duplicated across the pair; term
    // zeroed on odd lanes so each row sums once)
    float bvv = val; int bR = vRow; float bss = term;
#pragma unroll
    for (int mm = 1; mm <= 32; mm <<= 1) {
      float ov = __shfl_xor(bvv, mm, 64);
      int   oR = __shfl_xor(bR,  mm, 64);
      float os = __shfl_xor(bss, mm, 64);
      bss += os;
      if (ov > bvv || (ov == bvv && oR < bR)) { bvv = ov; bR = oR; }
    }

    // candidate A2 prefetch into registers BEFORE the barrier: each wave loads
    // its local winner's row slice; the final winner is one of the 8, so the
    // HBM latency overlaps the barrier + final reduce.
    double pf0 = 0.0, pf1 = 0.0;
    bool havePf = false;
    if (MODE == 1 && step > 0 && step + 1 < NSTEPS && (unsigned)bR <= 255u) {
      const double* ap = A2 + (size_t)(b256 + bR) * NH + (l << 1);
      pf0 = ap[0]; pf1 = ap[1];
      havePf = true;
    }

    if (l == 0) { sh.m.redV[w] = bvv; sh.m.redI[w] = bR; sh.m.redS[w] = bss; }
    __syncthreads();  // B_red

    float BV = sh.m.redV[0]; int BR = sh.m.redI[0];
#pragma unroll
    for (int k = 1; k < 8; ++k) {
      float ov = sh.m.redV[k]; int oR = sh.m.redI[k];
      if (ov > BV || (ov == BV && oR < BR)) { BV = ov; BR = oR; }
    }
    if ((unsigned)BR > 255u) BR = 0;
    const int BI = BR;
    const int jj = (int)pos_c[BI];

    if (t == 0) {
      float SS = (sh.m.redS[0] + sh.m.redS[1]) + (sh.m.redS[2] + sh.m.redS[3]);
      SS += (sh.m.redS[4] + sh.m.redS[5]) + (sh.m.redS[6] + sh.m.redS[7]);
      float lp = sh.m.logitArr[BI] - (float)log((double)SS);
      out[(size_t)b * NSTEPS + step] = (float)BI;
      out[(size_t)NBATCH * NSTEPS + (size_t)b * NSTEPS + step] = lp;
      nActSh[cur ^ 1] = nA - 1;
      jSh[cur ^ 1] = (jj < nA - 1) ? jj : -1;
    }

    if (t < NS) {
      int donorRow = (int)rowId_c[nA - 1];
      short rid = (t == jj) ? (short)donorRow : rowId_c[t];
      rowId_n[t] = rid;
      if (t < nA - 1) pos_n[rid] = (short)t;
    }
    // donor pair hands its refr slice to the adopter (read next step)
    if (jj < nA - 1 && i == nA - 1) {
      float4* rs4 = (float4*)(refScratch + hb);
#pragma unroll
      for (int q = 0; q < 16; ++q)
        rs4[q] = make_float4(refr[4 * q + 0], refr[4 * q + 1],
                             refr[4 * q + 2], refr[4 * q + 3]);
    }

    // next-step gumbel (both lanes; overlaps qq update / prefetch wait)
    if (step + 1 < NSTEPS && i < nA - 1) {
      int ridN = (i == jj) ? (int)rowId_c[nA - 1] : myRow;
      g = gumbel_of(sh.m.keyL[step + 1], (uint32_t)(b256 + ridN));
    }

    // ---- qq update ----
    if (step + 1 < NSTEPS) {
      if (MODE == 1) {
        if (step == 0) {
          const int hq = t >> 2, kq = t & 3;
          const float4* hrow = (const float4*)(cv + (size_t)(b256 + BI) * NE + kq * 32);
          const float4* m1p  = (const float4*)(M1T + (size_t)hq * NE + kq * 32);
          double am = dot32(hrow, m1p);
          am += __shfl_xor(am, 1, 64);
          am += __shfl_xor(am, 2, 64);
          if (kq == 0) {
            double dbase = qqbase[(size_t)b * NH + hq] + am;
            sh.m.base128[hq] = dbase;
            sh.m.qq[hq] = (float)(dbase + A2[(size_t)(b256 + BI) * NH + hq]);
          }
        } else if (havePf && bR == BI) {
          // winning wave(s): prefetched regs hold the right row
          const int h0 = l << 1;
          sh.m.qq[h0]     = (float)(sh.m.base128[h0]     + pf0);
          sh.m.qq[h0 + 1] = (float)(sh.m.base128[h0 + 1] + pf1);
        }
      } else {
        const int hq = t >> 2, kq = t & 3;
        const float4* hrow = (const float4*)(cv + (size_t)(b256 + BI) * NE + kq * 32);
        const float4* m2p  = (const float4*)(M2T + (size_t)hq * NE + kq * 32);
        double a2 = dot32(hrow, m2p);
        a2 += __shfl_xor(a2, 1, 64);
        a2 += __shfl_xor(a2, 2, 64);
        if (step == 0) {
          const float4* m1p = (const float4*)(M1T + (size_t)hq * NE + kq * 32);
          double am = dot32(hrow, m1p);
          am += __shfl_xor(am, 1, 64);
          am += __shfl_xor(am, 2, 64);
          if (kq == 0) {
            double dbase = qqbase[(size_t)b * NH + hq] + am;
            sh.m.base128[hq] = dbase;
            sh.m.qq[hq] = (float)(dbase + a2);
          }
        } else if (kq == 0) {
          sh.m.qq[hq] = (float)(sh.m.base128[hq] + a2);
        }
      }
    }
    __syncthreads();  // B3
  }
}

// ======================= round-2 passing kernel (no-ws fallback, unchanged) ==========
__device__ __forceinline__ float fast_tanh_ref(float x) {
  const float Chi = 2.8853900432586670f;
  const float Clo = 3.8519259822379735e-08f;
  float m = fmaf(x, Chi, x * Clo);
  float tt = exp2f(m);
  return 1.0f - 2.0f / (tt + 1.0f);
}

struct MainShR {
  float  query[NE];
  float  qq[NH];
  float  hbar[NE];
  float  inith[NE];
  float  hcur[NE];
  alignas(16) double vvd[NH];
  float  logitArr[NS];
  float  maskArr[NS];
  uint2  keyL[NSTEPS];
  float  meanv[NE];
  float  redV[4];
  int    redI[4];
  double redS[4];
  int    idxSh;
};
struct PreShR {
  float cvS[NS][33];
  float wS[32][NH];
};

__global__ __launch_bounds__(256, 2)
void decoder_kernel_ref(const float* __restrict__ cv, const float* __restrict__ mask_in,
                        const float* __restrict__ liw, const float* __restrict__ Wc,
                        const float* __restrict__ bc, const float* __restrict__ Wv,
                        const float* __restrict__ bv, const float* __restrict__ Wq,
                        const float* __restrict__ Wref, const float* __restrict__ vvec,
                        float* __restrict__ out) {
  const int b = blockIdx.x;
  const int t = threadIdx.x;
  const int b256 = b << 8;
  __shared__ union { PreShR pre; MainShR m; } sh;

  float refr[NH];
#pragma unroll
  for (int h = 0; h < NH; ++h) refr[h] = 0.0f;
  for (int ec = 0; ec < 4; ++ec) {
    const int e0 = ec * 32;
    __syncthreads();
    for (int i = t; i < 32 * NH; i += 256) {
      int r = i >> 7, h = i & 127;
      sh.pre.wS[r][h] = Wref[(e0 + r) * NH + h];
    }
    for (int i = t; i < NS * 32; i += 256) {
      int s2 = i >> 5, j = i & 31;
      sh.pre.cvS[s2][j] = cv[((size_t)b256 + s2) * NE + e0 + j];
    }
    __syncthreads();
#pragma unroll
    for (int hc = 0; hc < 16; ++hc) {
      double a[8] = {0,0,0,0,0,0,0,0};
      for (int e = 0; e < 32; ++e) {
        double cd = (double)sh.pre.cvS[t][e];
#pragma unroll
        for (int j = 0; j < 8; ++j) a[j] += cd * (double)sh.pre.wS[e][hc * 8 + j];
      }
#pragma unroll
      for (int j = 0; j < 8; ++j) refr[hc * 8 + j] += (float)a[j];
    }
  }
  __syncthreads();

  if (t < NSTEPS) {
    uint32_t o0, o1;
    tf2x32(0u, 42u, 0u, (uint32_t)t, o0, o1);
    sh.m.keyL[t] = make_uint2(o0, o1);
  }
  if (t < NH) sh.m.vvd[t] = (double)vvec[t];
  sh.m.maskArr[t] = (mask_in[(size_t)b256 + t] > 0.0f || t == 0) ? 1.0f : 0.0f;
  if (t < NE) {
    double s64 = 0.0;
    for (int s2 = 0; s2 < NS; ++s2) s64 += (double)cv[((size_t)b256 + s2) * NE + t];
    sh.m.meanv[t] = (float)(s64 * (1.0 / 256.0));
  }
  __syncthreads();
  if (t < NE) {
    double acc = 0.0;
    for (int e = 0; e < NE; ++e) acc += (double)sh.m.meanv[e] * (double)Wc[e * NE + t];
    float hbv = (float)acc + bc[t];
    sh.m.hbar[t] = hbv;
    double acc2 = 0.0;
    for (int k = 0; k < 2 * NE; ++k) acc2 += (double)liw[k] * (double)Wv[k * NE + t];
    float r0 = (float)acc2 + bv[t];
    sh.m.query[t] = hbv + r0;
  }
  __syncthreads();

  for (int step = 0; step < NSTEPS; ++step) {
    if (t < NH) {
      double acc = 0.0;
      for (int k = 0; k < NE; ++k) acc += (double)sh.m.query[k] * (double)Wq[k * NH + t];
      sh.m.qq[t] = (float)acc;
    }
    __syncthreads();

    float logit;
    bool masked = (sh.m.maskArr[t] != 0.0f);
    if (!masked) {
      double a0 = 0.0, a1 = 0.0, a2 = 0.0, a3 = 0.0;
      const float4*  qq4 = (const float4*)sh.m.qq;
      const double2* vv2 = (const double2*)sh.m.vvd;
#pragma unroll
      for (int h4 = 0; h4 < 32; ++h4) {
        float4  q  = qq4[h4];
        double2 va = vv2[2 * h4];
        double2 vb = vv2[2 * h4 + 1];
        a0 += (double)fast_tanh_ref(q.x + refr[4 * h4 + 0]) * va.x;
        a1 += (double)fast_tanh_ref(q.y + refr[4 * h4 + 1]) * va.y;
        a2 += (double)fast_tanh_ref(q.z + refr[4 * h4 + 2]) * vb.x;
        a3 += (double)fast_tanh_ref(q.w + refr[4 * h4 + 3]) * vb.y;
      }
      float u_ = (float)((a0 + a1) + (a2 + a3));
      logit = 10.0f * (float)tanh((double)u_);
    } else {
      logit = NEGINF;
    }
    sh.m.logitArr[t] = logit;

    uint2 key = sh.m.keyL[step];
    uint32_t j = (uint32_t)(b256 + t);
    uint32_t o0, o1;
    tf2x32(key.x, key.y, 0u, j, o0, o1);
    uint32_t bits = o0 ^ o1;
    float f = __uint_as_float((bits >> 9) | 0x3f800000u) - 1.0f;
    float u = (f == 0.0f) ? 1.17549435e-38f : f;
    float l1 = (float)(-log((double)u));
    float g  = (float)(-log((double)l1));
    float val = logit + g;
    double term = exp((double)logit);

    float bv_ = val; int bi = t; double bs = term;
#pragma unroll
    for (int m = 1; m <= 32; m <<= 1) {
      float  ov = __shfl_xor(bv_, m, 64);
      int    oi = __shfl_xor(bi,  m, 64);
      double os = __shfl_xor(bs,  m, 64);
      if (ov > bv_ || (ov == bv_ && oi < bi)) { bv_ = ov; bi = oi; }
      bs += os;
    }
    int w = t >> 6;
    if ((t & 63) == 0) { sh.m.redV[w] = bv_; sh.m.redI[w] = bi; sh.m.redS[w] = bs; }
    __syncthreads();

    if (t == 0) {
      float BV = sh.m.redV[0]; int BI = sh.m.redI[0];
      for (int k = 1; k < 4; ++k) {
        float ov = sh.m.redV[k]; int oi = sh.m.redI[k];
        if (ov > BV || (ov == BV && oi < BI)) { BV = ov; BI = oi; }
      }
      double SS = ((sh.m.redS[0] + sh.m.redS[1]) + (sh.m.redS[2] + sh.m.redS[3]));
      sh.m.idxSh = BI;
      float lp = sh.m.logitArr[BI] - (float)log(SS);
      out[(size_t)b * NSTEPS + step] = (float)BI;
      out[(size_t)NBATCH * NSTEPS + (size_t)b * NSTEPS + step] = lp;
    }
    __syncthreads();

    int idx = sh.m.idxSh;
    if (t == idx) sh.m.maskArr[t] = 1.0f;
    if (t < NE) {
      float hc = cv[((size_t)b256 + idx) * NE + t];
      sh.m.hcur[t] = hc;
      if (step == 0) sh.m.inith[t] = hc;
    }
    __syncthreads();

    if (t < NE) {
      double acc2 = 0.0;
      for (int k = 0; k < NE; ++k) acc2 += (double)sh.m.inith[k] * (double)Wv[k * NE + t];
      for (int k = 0; k < NE; ++k) acc2 += (double)sh.m.hcur[k] * (double)Wv[(NE + k) * NE + t];
      float mm = (float)acc2 + bv[t];
      sh.m.query[t] = sh.m.hbar[t] + mm;
    }
    __syncthreads();
  }
}

extern "C" void kernel_launch(void* const* d_in, const int* in_sizes, int n_in,
                              void* d_out, int out_size, void* d_ws, size_t ws_size,
                              hipStream_t stream) {
  const float* cv   = (const float*)d_in[0];
  const float* mask = (const float*)d_in[2];
  const float* liw  = (const float*)d_in[3];
  const float* Wc   = (const float*)d_in[4];
  const float* bc   = (const float*)d_in[5];
  const float* Wv   = (const float*)d_in[6];
  const float* bv   = (const float*)d_in[7];
  const float* Wq   = (const float*)d_in[8];
  const float* Wref = (const float*)d_in[9];
  const float* vv   = (const float*)d_in[10];
  (void)in_sizes; (void)n_in; (void)out_size;

  const size_t SZ_QQB = (size_t)NBATCH * NH * sizeof(double);     // 512 KB
  const size_t SZ_M   = (size_t)NE * NH * sizeof(float);          // 64 KB each
  const size_t SZ_QQ0 = (size_t)NBATCH * NH * sizeof(float);      // 256 KB
  const size_t SZ_A2  = (size_t)NBATCH * NS * NH * sizeof(double);// 134 MB
  const size_t need_min = SZ_QQB + 2 * SZ_M + SZ_QQ0 + 512;
  const size_t need_pre = need_min + SZ_A2;

  if (ws_size >= need_min) {
    char* p = (char*)d_ws;
    double* qqbase = (double*)p;            p += SZ_QQB;
    float*  M1T    = (float*)p;             p += SZ_M;
    float*  M2T    = (float*)p;             p += SZ_M;
    float*  qq0    = (float*)p;             p += SZ_QQ0;
    float*  rest0  = (float*)p;             p += 512;
    double* A2     = (double*)p;

    k1_mats<<<257, 128, 0, stream>>>(Wv, Wq, liw, bv, M1T, M2T, rest0);
    k2_base<<<NBATCH, 128, 0, stream>>>(cv, Wc, bc, bv, Wq, rest0, qqbase, qq0);
    if (ws_size >= need_pre) {
      k_a2v3<<<NBATCH * 8, 256, 0, stream>>>(cv, M2T, A2);
      decode_main<1><<<NBATCH, 512, 0, stream>>>(cv, mask, Wref, vv, qqbase, M1T,
                                                 M2T, qq0, A2, (float*)d_out);
    } else {
      decode_main<0><<<NBATCH, 512, 0, stream>>>(cv, mask, Wref, vv, qqbase, M1T,
                                                 M2T, qq0, nullptr, (float*)d_out);
    }
  } else {
    decoder_kernel_ref<<<NBATCH, 256, 0, stream>>>(cv, mask, liw, Wc, bc, Wv, bv,
                                                   Wq, Wref, vv, (float*)d_out);
  }
}